// Round 13
// baseline (2100.538 us; speedup 1.0000x reference)
//
#include <hip/hip_runtime.h>
#include <hip/hip_fp16.h>

#define NA 100000
#define NBATCH 4096
#define MLD 68
#define CLD2 66

typedef _Float16 f16;
typedef f16 half8 __attribute__((ext_vector_type(8)));
typedef f16 half4 __attribute__((ext_vector_type(4)));
typedef float f32x4 __attribute__((ext_vector_type(4)));
union H8 { uint4 u; __half h[8]; };
union HU { uint4 u; half8 h; f16 s[8]; };

// packed f16 atomic add: HIP has no atomicAdd(__half2*); use the HW pk_add_f16 path.
__device__ inline void pk_atomic_add(__half2* addr, __half2 v) {
#if __has_builtin(__builtin_amdgcn_flat_atomic_fadd_v2f16)
  typedef _Float16 hv2 __attribute__((ext_vector_type(2)));
  __builtin_amdgcn_flat_atomic_fadd_v2f16((hv2*)addr, *(hv2*)&v);
#else
  unsafeAtomicAdd(addr, v);
#endif
}

// ---------------- counts (all 5 maps + batch) ----------------

struct MapsParams {
  const int* row[6];
  int cnt_off[6];
  int start[6];
  int total;
};

__global__ __launch_bounds__(256) void k_count(MapsParams mp, int* cnt) {
  for (int g = blockIdx.x * 256 + threadIdx.x; g < mp.total; g += gridDim.x * 256) {
    int m = 0;
#pragma unroll
    for (int i = 1; i < 6; i++) if (g >= mp.start[i]) m = i;
    int e = g - mp.start[m];
    atomicAdd(&cnt[mp.cnt_off[m] + mp.row[m][e]], 1);
  }
}

__global__ __launch_bounds__(256) void k_scan_batch(const int* cntb, int* basea) {
  __shared__ int s[256];
  int t = threadIdx.x;
  int carry = 0;
  for (int c0 = 0; c0 < NBATCH; c0 += 256) {
    int v = cntb[c0 + t];
    s[t] = v;
    __syncthreads();
    for (int d = 1; d < 256; d <<= 1) {
      int x = (t >= d) ? s[t - d] : 0;
      __syncthreads();
      s[t] += x;
      __syncthreads();
    }
    basea[c0 + t] = s[t] - v + carry;
    int tot = s[255];
    __syncthreads();
    carry += tot;
  }
}

__global__ __launch_bounds__(256) void k_fill_batch(const int* batch, int* cursor, int* bucket) {
  for (int a = blockIdx.x * 256 + threadIdx.x; a < NA; a += gridDim.x * 256) {
    int b = batch[a];
    int pos = atomicAdd(&cursor[b], 1);
    bucket[pos] = a;
  }
}

// ---------------- feature init ----------------

__global__ __launch_bounds__(256) void k_atom_init(const int* xa, const float* e0,
                                                   const float* e1, const float* e2, float* x) {
  int idx = blockIdx.x * 256 + threadIdx.x;  // float4 index
  if (idx >= NA * 16) return;
  int a = idx >> 4, q = idx & 15;
  int f0 = xa[a * 3], f1 = xa[a * 3 + 1], f2 = xa[a * 3 + 2];
  float4 v0 = ((const float4*)e0)[f0 * 16 + q];
  float4 v1 = ((const float4*)e1)[f1 * 16 + q];
  float4 v2 = ((const float4*)e2)[f2 * 16 + q];
  float4 o;
  o.x = v0.x + v1.x + v2.x; o.y = v0.y + v1.y + v2.y;
  o.z = v0.z + v1.z + v2.z; o.w = v0.w + v1.w + v2.w;
  ((float4*)x)[idx] = o;
}

// snapshot: xh = f16(x)
__global__ __launch_bounds__(256) void k_snap(const float* x, f16* xh) {
  int idx = blockIdx.x * 256 + threadIdx.x;
  if (idx >= NA * 16) return;
  float4 v = ((const float4*)x)[idx];
  half4 h = {(f16)v.x, (f16)v.y, (f16)v.z, (f16)v.w};
  ((half4*)xh)[idx] = h;
}

struct PInit {
  __half* dst[5];
  const int* vals[5];
  const float* tab[5];
  int start8[5];  // cumulative half8-chunk starts
  int total8;
};

__global__ __launch_bounds__(256) void k_path_init(PInit pp) {
  for (int g = blockIdx.x * 256 + threadIdx.x; g < pp.total8; g += gridDim.x * 256) {
    int m = 0;
#pragma unroll
    for (int i = 1; i < 5; i++) if (g >= pp.start8[i]) m = i;
    int lc = g - pp.start8[m];
    int e = lc >> 3, q = lc & 7;
    int v = pp.vals[m][e];
    const float* src = pp.tab[m] + v * 64 + q * 8;
    H8 o;
#pragma unroll
    for (int j = 0; j < 8; j++) o.h[j] = __float2half(src[j]);
    ((uint4*)pp.dst[m])[lc] = o.u;
  }
}

// ---------------- prepack conv kernels to fp16 MFMA-B layout ----------------

__global__ __launch_bounds__(256) void k_prepB(const float* pK, const float* cK, f16* Bp) {
  int tid = blockIdx.x * 256 + threadIdx.x;
  if (tid >= 10 * 12288) return;
  int set = tid / 12288, pos = tid % 12288;
  int j = pos & 7, lane = (pos >> 3) & 63, kcnt = pos >> 9;
  int kc = kcnt % 6, nt = kcnt / 6;
  int k = kc * 32 + ((lane >> 4) << 3) + j;
  int n = (nt << 4) + (lane & 15);
  int w = k >> 6, ji = k & 63;
  const float* K = (set < 6) ? (pK + set * 3 * 4096) : (cK + (set - 6) * 3 * 4096);
  float v = K[w * 4096 + ji * 64 + n];
  if (set >= 6) v = 0.5f * (v + K[(2 - w) * 4096 + ji * 64 + n]);
  Bp[tid] = (f16)v;
}

// ---------------- prepack 64x64 weights to fp16 MFMA-B layout ----------------
// sets 0..5 pW_p2a, 6..9 cW_p2a, 10..15 pW_a2p, 16..19 cW_a2p

__global__ __launch_bounds__(256) void k_prepW(const float* pW, const float* cW,
                                               const float* pWa, const float* cWa, f16* Wp) {
  int tid = blockIdx.x * 256 + threadIdx.x;
  if (tid >= 20 * 4096) return;
  int set = tid >> 12, pos = tid & 4095;
  int j = pos & 7, lane = (pos >> 3) & 63, ntkc = pos >> 9;
  int kc = ntkc & 1, nt = ntkc >> 1;
  int k = kc * 32 + ((lane >> 4) << 3) + j;
  int n = (nt << 4) + (lane & 15);
  const float* W;
  if (set < 6) W = pW + set * 4096;
  else if (set < 10) W = cW + (set - 6) * 4096;
  else if (set < 16) W = pWa + (set - 10) * 4096;
  else W = cWa + (set - 16) * 4096;
  Wp[tid] = (f16)W[k * 64 + n];
}

// ---------------- fused a2p+conv+scatter, one map per launch ----------------
//   t = xp_old + relu(gather(xh) @ Wa + ba)
//   xp_new = t + relu(conv3(t) @ K + Kb)      -> global write
//   acc[row_atom[e]] += xp_new[e]             -> pk f16 atomics

struct FusedParams {
  const f16* xh;
  const int* gidx;
  __half* xp;
  __half2* acc;
  const f16* Wa;
  const float* ba;
  const f16* Bp;
  const float* Kb;
  int kk, P, ppb, cyclic;
};

__global__ __launch_bounds__(256) void k_fused(FusedParams p) {
  __shared__ uint4 CfU[1584];   // 25.3KB: a2p A-frags (<=12.3KB), then fp32 C tile [96xCLD2]
  __shared__ uint4 xn4[873];    // 14KB: xnew f16, 97 rows x 9 uint4 (row 96 = zeros)
  __shared__ float bl[64], kbl[64];
  __shared__ int ridx[96];
  float* Cf = (float*)CfU;
  uint4* Af = CfU;
  int kk = p.kk, cyc = p.cyclic;
  int t = threadIdx.x;
  int p0 = blockIdx.x * p.ppb;
  int np = min(p.ppb, p.P - p0);
  int R = np * kk;      // multiple of 16 (64..96)
  int mtb = R >> 4;
  long ebase = (long)p0 * kk;
  if (t < 64) { bl[t] = p.ba[t]; kbl[t] = p.Kb[t]; }
  if (t < 9) { uint4 z; z.x = z.y = z.z = z.w = 0; xn4[96 * 9 + t] = z; }
  if (t < R) ridx[t] = p.gidx[ebase + t];
  __syncthreads();
  // ---- a2p A-frag fill, dest-major (conflict-free LDS writes)
  const uint4* xh4 = (const uint4*)p.xh;
  int nunits = mtb * 128;
  for (int j = t; j < nunits; j += 256) {
    int frag = j >> 6, lb = j & 63;
    int row = ((frag >> 1) << 4) + (lb & 15);
    int ch = ((frag & 1) << 2) + (lb >> 4);
    Af[j] = xh4[(long)ridx[row] * 8 + ch];
  }
  __syncthreads();
  int lane = t & 63, wid = t >> 6;
  int wave_n = wid & 1, wave_m = wid >> 1;
  int mtA = (mtb + 1) >> 1;
  int m0 = wave_m ? mtA : 0;
  int mcnt = wave_m ? (mtb - mtA) : mtA;  // <= 3
  // ---- a2p MFMA
  f32x4 acc1[3][2];
#pragma unroll
  for (int i = 0; i < 3; i++)
#pragma unroll
    for (int jn = 0; jn < 2; jn++) { f32x4 z = {0.f, 0.f, 0.f, 0.f}; acc1[i][jn] = z; }
  const uint4* Wau = (const uint4*)p.Wa;
#pragma unroll
  for (int kc = 0; kc < 2; kc++) {
    HU a[3], b[2];
#pragma unroll
    for (int jn = 0; jn < 2; jn++)
      b[jn].u = Wau[(((wave_n * 2 + jn) << 1) + kc) * 64 + lane];
#pragma unroll
    for (int i = 0; i < 3; i++)
      if (i < mcnt) a[i].u = Af[(((m0 + i) << 1) + kc) * 64 + lane];
#pragma unroll
    for (int i = 0; i < 3; i++)
      if (i < mcnt) {
#pragma unroll
        for (int jn = 0; jn < 2; jn++)
          acc1[i][jn] = __builtin_amdgcn_mfma_f32_16x16x32_f16(a[i].h, b[jn].h, acc1[i][jn], 0, 0, 0);
      }
  }
  __syncthreads();  // Af reads done; Cf may overwrite
  // ---- a2p epilogue -> Cf
#pragma unroll
  for (int i = 0; i < 3; i++) {
    if (i >= mcnt) continue;
#pragma unroll
    for (int jn = 0; jn < 2; jn++) {
      int n = ((wave_n * 2 + jn) << 4) + (lane & 15);
      float bv = bl[n];
      int rb = ((m0 + i) << 4) + ((lane >> 4) << 2);
#pragma unroll
      for (int reg = 0; reg < 4; reg++) {
        float v = acc1[i][jn][reg] + bv;
        Cf[(rb + reg) * CLD2 + n] = v > 0.f ? v : 0.f;
      }
    }
  }
  __syncthreads();
  // ---- t = xp_old + relu(...) -> xnew (LDS, stride-9: conflict-free)
  uint4* xg = (uint4*)(p.xp + (long)ebase * 64);
  for (int idx = t; idx < R * 8; idx += 256) {
    int row = idx >> 3, ch = idx & 7;
    HU res; res.u = xg[idx];
    const float* c = &Cf[row * CLD2 + ch * 8];
    HU o;
#pragma unroll
    for (int j = 0; j < 8; j++) o.s[j] = (f16)((float)res.s[j] + c[j]);
    xn4[row * 9 + ch] = o.u;
  }
  __syncthreads();
  // ---- conv MFMA: A-frags from xnew with shifted rows
  f32x4 acc2[3][2];
#pragma unroll
  for (int i = 0; i < 3; i++)
#pragma unroll
    for (int jn = 0; jn < 2; jn++) { f32x4 z = {0.f, 0.f, 0.f, 0.f}; acc2[i][jn] = z; }
  int rdw[3][3];
#pragma unroll
  for (int i = 0; i < 3; i++) {
    if (i >= mcnt) continue;
    int mr = ((m0 + i) << 4) + (lane & 15);
    int sm = mr % kk;
    rdw[i][1] = mr;
    rdw[i][0] = (sm >= 1) ? mr - 1 : (cyc ? mr + kk - 1 : 96);
    rdw[i][2] = (sm + 1 < kk) ? mr + 1 : (cyc ? mr + 1 - kk : 96);
  }
  const uint4* Bg = (const uint4*)p.Bp;
  for (int kc = 0; kc < 6; kc++) {
    int w = kc >> 1;
    int chunk = ((kc & 1) << 2) + (lane >> 4);
    HU a[3], b[2];
#pragma unroll
    for (int jn = 0; jn < 2; jn++)
      b[jn].u = Bg[((wave_n * 2 + jn) * 6 + kc) * 64 + lane];
#pragma unroll
    for (int i = 0; i < 3; i++)
      if (i < mcnt) a[i].u = xn4[rdw[i][w] * 9 + chunk];
#pragma unroll
    for (int i = 0; i < 3; i++)
      if (i < mcnt) {
#pragma unroll
        for (int jn = 0; jn < 2; jn++)
          acc2[i][jn] = __builtin_amdgcn_mfma_f32_16x16x32_f16(a[i].h, b[jn].h, acc2[i][jn], 0, 0, 0);
      }
  }
  __syncthreads();  // xnew-combine Cf reads done; Cf overwrite OK
  // ---- conv epilogue -> Cf
#pragma unroll
  for (int i = 0; i < 3; i++) {
    if (i >= mcnt) continue;
#pragma unroll
    for (int jn = 0; jn < 2; jn++) {
      int n = ((wave_n * 2 + jn) << 4) + (lane & 15);
      float bv = kbl[n];
      int rb = ((m0 + i) << 4) + ((lane >> 4) << 2);
#pragma unroll
      for (int reg = 0; reg < 4; reg++) {
        float v = acc2[i][jn][reg] + bv;
        Cf[(rb + reg) * CLD2 + n] = v > 0.f ? v : 0.f;
      }
    }
  }
  __syncthreads();
  // ---- final: xp_new = xnew + relu-conv; global write + scatter atomics
  for (int idx = t; idx < R * 8; idx += 256) {
    int row = idx >> 3, ch = idx & 7;
    HU res; res.u = xn4[row * 9 + ch];
    const float* c = &Cf[row * CLD2 + ch * 8];
    HU o;
#pragma unroll
    for (int j = 0; j < 8; j++) o.s[j] = (f16)((float)res.s[j] + c[j]);
    xg[idx] = o.u;
    int atom = ridx[row];
    __half2* ap = &p.acc[(long)atom * 32 + ch * 4];
    unsigned int dw[4] = {o.u.x, o.u.y, o.u.z, o.u.w};
#pragma unroll
    for (int j = 0; j < 4; j++) pk_atomic_add(&ap[j], *(__half2*)&dw[j]);
  }
}

// ---------------- p2a apply: x += relu(acc/cnt @ W + b); self-zeroes f16 acc ----------------

__global__ __launch_bounds__(256) void k_apply(f16* acc, const int* cnt, const f16* Wp,
                                               const float* bias, float* x) {
  __shared__ float mean[64 * MLD];  // 17.4KB
  __shared__ uint4 Af[512];         // 8KB fp16 A-frags
  __shared__ float invl[64];
  __shared__ float bl[64];
  int t = threadIdx.x;
  int a0 = blockIdx.x * 64;
  if (t < 64) {
    int cb = cnt[a0 + t];
    invl[t] = 1.f / (float)(cb > 0 ? cb : 1);
    bl[t] = bias[t];
  }
  uint4* acc4 = (uint4*)acc;  // 8 halves per uint4; 64 rows x 8 = 512 per tile
#pragma unroll
  for (int i = 0; i < 2; i++) {
    int idx = t + 256 * i;
    int r = idx >> 3, q = idx & 7;
    HU v; v.u = acc4[(long)a0 * 8 + idx];
    uint4 z4; z4.x = z4.y = z4.z = z4.w = 0;
    acc4[(long)a0 * 8 + idx] = z4;  // ready for next map
    float* mr = &mean[r * MLD + q * 8];
#pragma unroll
    for (int j = 0; j < 8; j++) mr[j] = (float)v.s[j];
  }
  __syncthreads();
  // dest-major A-frag fill (conflict-free LDS writes)
#pragma unroll
  for (int i = 0; i < 2; i++) {
    int j = t + 256 * i;
    int frag = j >> 6, lb = j & 63;
    int row = ((frag >> 1) << 4) + (lb & 15);
    int ch = ((frag & 1) << 2) + (lb >> 4);
    float inv = invl[row];
    const float* mr = &mean[row * MLD + ch * 8];
    HU o;
#pragma unroll
    for (int jj = 0; jj < 8; jj++) o.h[jj] = (f16)(mr[jj] * inv);
    Af[j] = o.u;
  }
  __syncthreads();
  int lane = t & 63, wid = t >> 6;
  HU af0, af1;
  af0.u = Af[((wid << 1) + 0) * 64 + lane];
  af1.u = Af[((wid << 1) + 1) * 64 + lane];
  const uint4* Wu = (const uint4*)Wp;
  int rowb = a0 + wid * 16 + ((lane >> 4) << 2);
#pragma unroll
  for (int nt = 0; nt < 4; nt++) {
    HU b0, b1;
    b0.u = Wu[((nt << 1) + 0) * 64 + lane];
    b1.u = Wu[((nt << 1) + 1) * 64 + lane];
    f32x4 z = {0.f, 0.f, 0.f, 0.f};
    z = __builtin_amdgcn_mfma_f32_16x16x32_f16(af0.h, b0.h, z, 0, 0, 0);
    z = __builtin_amdgcn_mfma_f32_16x16x32_f16(af1.h, b1.h, z, 0, 0, 0);
    int n = nt * 16 + (lane & 15);
    float bv = bl[n];
#pragma unroll
    for (int r = 0; r < 4; r++) {
      int atom = rowb + r;
      if (atom < NA) {
        float vv = z[r] + bv;
        vv = vv > 0.f ? vv : 0.f;
        x[(long)atom * 64 + n] += vv;
      }
    }
  }
}

// ---------------- batch mean: g1[b] = mean(x[a]) over CSR bucket ----------------

__global__ __launch_bounds__(256) void k_meanscatter(const float* src, const int* bucket,
                                                     const int* basea, const int* cnta,
                                                     float* dst, int nseg) {
  int wid = (blockIdx.x * 256 + threadIdx.x) >> 6;
  int lane = threadIdx.x & 63;
  if (wid >= nseg) return;
  int b0 = basea[wid], cnt = cnta[wid];
  float s = 0.f;
  for (int i = 0; i < cnt; i++) {
    int e = bucket[b0 + i];
    s += src[(long)e * 64 + lane];
  }
  dst[(long)wid * 64 + lane] = s / (float)(cnt > 0 ? cnt : 1);
}

// ---------------- head gemm: g2 = relu(g1 @ W + b) ----------------

__global__ __launch_bounds__(256) void k_head(const float* g1, const float* W,
                                              const float* bias, float* g2) {
  __shared__ float Wl[4096];
  __shared__ float inl[32 * 64];
  __shared__ float bl[64];
  int t = threadIdx.x;
  int brow = blockIdx.x * 32;
#pragma unroll
  for (int i = 0; i < 4; i++) ((float4*)Wl)[t + 256 * i] = ((const float4*)W)[t + 256 * i];
  if (t < 64) bl[t] = bias[t];
  __syncthreads();
#pragma unroll
  for (int i = 0; i < 2; i++) {
    int idx = t + 256 * i;
    int r = idx >> 4, q = idx & 15;
    ((float4*)inl)[idx] = ((const float4*)(g1 + (long)(brow + r) * 64))[q];
  }
  __syncthreads();
  int c = t & 63, rq = t >> 6;
  float acc[8];
#pragma unroll
  for (int i = 0; i < 8; i++) acc[i] = 0.f;
  for (int j = 0; j < 64; j += 4) {
    float w0 = Wl[(j + 0) * 64 + c], w1 = Wl[(j + 1) * 64 + c];
    float w2 = Wl[(j + 2) * 64 + c], w3 = Wl[(j + 3) * 64 + c];
#pragma unroll
    for (int i = 0; i < 8; i++) {
      int r = rq * 8 + i;
      float4 v = *(const float4*)&inl[r * 64 + j];
      acc[i] += v.x * w0 + v.y * w1 + v.z * w2 + v.w * w3;
    }
  }
#pragma unroll
  for (int i = 0; i < 8; i++) {
    long r = brow + rq * 8 + i;
    float v = acc[i] + bl[c];
    g2[r * 64 + c] = v > 0.f ? v : 0.f;
  }
}

__global__ __launch_bounds__(256) void k_final(const float* g2, const float* linW,
                                               const float* linb, float* out) {
  int wid = (blockIdx.x * 256 + threadIdx.x) >> 6;
  int lane = threadIdx.x & 63;
  if (wid >= NBATCH) return;
  float v = g2[(long)wid * 64 + lane] * linW[lane];
  for (int o = 32; o > 0; o >>= 1) v += __shfl_down(v, o, 64);
  if (lane == 0) out[wid] = v + linb[0];
}

__global__ __launch_bounds__(256) void k_zero_out(float* out, int n) {
  for (int i = blockIdx.x * 256 + threadIdx.x; i < n; i += gridDim.x * 256) out[i] = 0.f;
}

// ---------------- launcher ----------------

extern "C" void kernel_launch(void* const* d_in, const int* in_sizes, int n_in,
                              void* d_out, int out_size, void* d_ws, size_t ws_size,
                              hipStream_t stream) {
  (void)in_sizes; (void)n_in;

  const int* x_atom = (const int*)d_in[0];
  const int* vals[5] = {(const int*)d_in[1], (const int*)d_in[4], (const int*)d_in[7],
                        (const int*)d_in[10], (const int*)d_in[13]};
  const int* rowm[5] = {(const int*)d_in[2], (const int*)d_in[5], (const int*)d_in[8],
                        (const int*)d_in[11], (const int*)d_in[14]};
  const int* batch = (const int*)d_in[16];
  const float* aemb0 = (const float*)d_in[17];
  const float* aemb1 = (const float*)d_in[18];
  const float* aemb2 = (const float*)d_in[19];
  const float* path_emb = (const float*)d_in[20];
  const float* cycle_emb = (const float*)d_in[21];
  const float* pW_a2p = (const float*)d_in[22];
  const float* pb_a2p = (const float*)d_in[23];
  const float* pW_p2a = (const float*)d_in[24];
  const float* pb_p2a = (const float*)d_in[25];
  const float* pK = (const float*)d_in[26];
  const float* pKb = (const float*)d_in[27];
  const float* cW_a2p = (const float*)d_in[28];
  const float* cb_a2p = (const float*)d_in[29];
  const float* cW_p2a = (const float*)d_in[30];
  const float* cb_p2a = (const float*)d_in[31];
  const float* cK = (const float*)d_in[32];
  const float* cKb = (const float*)d_in[33];
  const float* alW = (const float*)d_in[34];
  const float* alb = (const float*)d_in[35];
  const float* linW = (const float*)d_in[36];
  const float* linb = (const float*)d_in[37];

  static const int Em[5] = {300000, 400000, 500000, 200000, 240000};
  static const int Km[5] = {3, 4, 5, 5, 6};
  static const int Ppb[5] = {32, 24, 16, 16, 16};
  const int CNT_N = 5 * 100000 + NBATCH;  // 504096
  const int ACC_ROWS = 100032;            // padded to apply grid (1563*64)

  char* ws = (char*)d_ws;
  size_t off = 0;
  auto alloc = [&](size_t nbytes) -> char* {
    char* p = ws + off;
    off = (off + nbytes + 255) & ~(size_t)255;
    return p;
  };
  float* x = (float*)alloc((size_t)NA * 64 * 4);
  f16* xh = (f16*)alloc((size_t)NA * 64 * 2);  // f16 snapshot for group-local gathers
  __half* xp[5];
  for (int m = 0; m < 5; m++) xp[m] = (__half*)alloc((size_t)Em[m] * 64 * 2);
  f16* acc = (f16*)alloc((size_t)ACC_ROWS * 64 * 2);  // f16 accumulator
  float* g1 = (float*)alloc((size_t)NBATCH * 64 * 4);
  float* g2 = (float*)alloc((size_t)NBATCH * 64 * 4);
  int* cnt = (int*)alloc((size_t)CNT_N * 4);
  int* basea_b = (int*)alloc((size_t)(NBATCH + 1) * 4);
  int* cursor_b = (int*)alloc((size_t)NBATCH * 4);
  int* bucket = (int*)alloc((size_t)NA * 4);
  f16* Bp = (f16*)alloc((size_t)10 * 12288 * 2);  // prepacked conv kernels
  f16* Wpk = (f16*)alloc((size_t)20 * 4096 * 2);  // prepacked p2a+a2p weights

  if (ws_size < off) {  // workspace too small: emit readable failure, not a fault
    k_zero_out<<<16, 256, 0, stream>>>((float*)d_out, out_size);
    return;
  }

  // ---- counts (all maps + batch) and batch CSR
  MapsParams mp;
  {
    int s = 0;
    for (int m = 0; m < 5; m++) {
      mp.row[m] = rowm[m]; mp.cnt_off[m] = m * 100000;
      mp.start[m] = s; s += Em[m];
    }
    mp.row[5] = batch; mp.cnt_off[5] = 500000; mp.start[5] = s;
    mp.total = s + NA;
  }
  (void)hipMemsetAsync(cnt, 0, (size_t)CNT_N * 4, stream);
  (void)hipMemsetAsync(acc, 0, (size_t)ACC_ROWS * 64 * 2, stream);
  k_count<<<2048, 256, 0, stream>>>(mp, cnt);
  k_scan_batch<<<1, 256, 0, stream>>>(cnt + 500000, basea_b);
  (void)hipMemcpyAsync(cursor_b, basea_b, (size_t)NBATCH * 4, hipMemcpyDeviceToDevice, stream);
  k_fill_batch<<<128, 256, 0, stream>>>(batch, cursor_b, bucket);

  // ---- prepack weights + feature init
  k_prepB<<<480, 256, 0, stream>>>(pK, cK, Bp);
  k_prepW<<<320, 256, 0, stream>>>(pW_p2a, cW_p2a, pW_a2p, cW_a2p, Wpk);
  k_atom_init<<<NA * 16 / 256, 256, 0, stream>>>(x_atom, aemb0, aemb1, aemb2, x);
  {
    PInit pp;
    int s8 = 0;
    for (int m = 0; m < 5; m++) {
      pp.dst[m] = xp[m];
      pp.vals[m] = vals[m];
      pp.tab[m] = (m < 3) ? (path_emb + m * 6 * 64) : (cycle_emb + (m - 3) * 4 * 64);
      pp.start8[m] = s8;
      s8 += Em[m] * 8;
    }
    pp.total8 = s8;
    k_path_init<<<8192, 256, 0, stream>>>(pp);
  }

  int apply_blocks = ACC_ROWS / 64;  // 1563
  int snap_blocks = NA * 16 / 256;   // 6250

  // ---- layers: per group, snapshot xh then per map: fused(a2p+conv+scatter) -> apply
  for (int l = 0; l < 2; l++) {
    // === paths group (maps 0..2), non-cyclic
    k_snap<<<snap_blocks, 256, 0, stream>>>(x, xh);
    for (int m = 0; m < 3; m++) {
      FusedParams fp{};
      fp.xh = xh; fp.gidx = rowm[m]; fp.xp = xp[m]; fp.acc = (__half2*)acc;
      fp.Wa = Wpk + (size_t)(10 + l * 3 + m) * 4096;
      fp.ba = pb_a2p + (l * 3 + m) * 64;
      fp.Bp = Bp + (size_t)(l * 3 + m) * 12288;
      fp.Kb = pKb + (l * 3 + m) * 64;
      fp.kk = Km[m]; fp.P = Em[m] / Km[m]; fp.ppb = Ppb[m]; fp.cyclic = 0;
      int blocks = (fp.P + fp.ppb - 1) / fp.ppb;
      k_fused<<<blocks, 256, 0, stream>>>(fp);
      k_apply<<<apply_blocks, 256, 0, stream>>>(acc, cnt + m * 100000,
                                                Wpk + (size_t)(l * 3 + m) * 4096,
                                                pb_p2a + (l * 3 + m) * 64, x);
    }
    // === cycles group (maps 3..4), cyclic
    k_snap<<<snap_blocks, 256, 0, stream>>>(x, xh);
    for (int m = 3; m < 5; m++) {
      int i = m - 3;
      FusedParams fp{};
      fp.xh = xh; fp.gidx = rowm[m]; fp.xp = xp[m]; fp.acc = (__half2*)acc;
      fp.Wa = Wpk + (size_t)(16 + l * 2 + i) * 4096;
      fp.ba = cb_a2p + (l * 2 + i) * 64;
      fp.Bp = Bp + (size_t)(6 + l * 2 + i) * 12288;
      fp.Kb = cKb + (l * 2 + i) * 64;
      fp.kk = Km[m]; fp.P = Em[m] / Km[m]; fp.ppb = Ppb[m]; fp.cyclic = 1;
      int blocks = (fp.P + fp.ppb - 1) / fp.ppb;
      k_fused<<<blocks, 256, 0, stream>>>(fp);
      k_apply<<<apply_blocks, 256, 0, stream>>>(acc, cnt + m * 100000,
                                                Wpk + (size_t)(6 + l * 2 + i) * 4096,
                                                cb_p2a + (l * 2 + i) * 64, x);
    }
  }

  // ---- head
  k_meanscatter<<<NBATCH / 4, 256, 0, stream>>>(x, bucket, basea_b, cnt + 500000,
                                                g1, NBATCH);
  k_head<<<NBATCH / 32, 256, 0, stream>>>(g1, alW, alb, g2);
  k_final<<<NBATCH / 4, 256, 0, stream>>>(g2, linW, linb, (float*)d_out);
}

// Round 14
// 1295.538 us; speedup vs baseline: 1.6214x; 1.6214x over previous
//
#include <hip/hip_runtime.h>
#include <hip/hip_fp16.h>

#define NA 100000
#define NBATCH 4096
#define MLD 68
#define CLD2 66

typedef _Float16 f16;
typedef f16 half8 __attribute__((ext_vector_type(8)));
typedef f16 half4 __attribute__((ext_vector_type(4)));
typedef float f32x4 __attribute__((ext_vector_type(4)));
union H8 { uint4 u; __half h[8]; };
union HU { uint4 u; half8 h; f16 s[8]; };

// packed f16 atomic add: HIP has no atomicAdd(__half2*); use the HW pk_add_f16 path.
__device__ inline void pk_atomic_add(__half2* addr, __half2 v) {
#if __has_builtin(__builtin_amdgcn_flat_atomic_fadd_v2f16)
  typedef _Float16 hv2 __attribute__((ext_vector_type(2)));
  __builtin_amdgcn_flat_atomic_fadd_v2f16((hv2*)addr, *(hv2*)&v);
#else
  unsafeAtomicAdd(addr, v);
#endif
}

// ---------------- counts (all 5 maps + batch) ----------------

struct MapsParams {
  const int* row[6];
  int cnt_off[6];
  int start[6];
  int total;
};

__global__ __launch_bounds__(256) void k_count(MapsParams mp, int* cnt) {
  for (int g = blockIdx.x * 256 + threadIdx.x; g < mp.total; g += gridDim.x * 256) {
    int m = 0;
#pragma unroll
    for (int i = 1; i < 6; i++) if (g >= mp.start[i]) m = i;
    int e = g - mp.start[m];
    atomicAdd(&cnt[mp.cnt_off[m] + mp.row[m][e]], 1);
  }
}

__global__ __launch_bounds__(256) void k_scan_batch(const int* cntb, int* basea) {
  __shared__ int s[256];
  int t = threadIdx.x;
  int carry = 0;
  for (int c0 = 0; c0 < NBATCH; c0 += 256) {
    int v = cntb[c0 + t];
    s[t] = v;
    __syncthreads();
    for (int d = 1; d < 256; d <<= 1) {
      int x = (t >= d) ? s[t - d] : 0;
      __syncthreads();
      s[t] += x;
      __syncthreads();
    }
    basea[c0 + t] = s[t] - v + carry;
    int tot = s[255];
    __syncthreads();
    carry += tot;
  }
}

__global__ __launch_bounds__(256) void k_fill_batch(const int* batch, int* cursor, int* bucket) {
  for (int a = blockIdx.x * 256 + threadIdx.x; a < NA; a += gridDim.x * 256) {
    int b = batch[a];
    int pos = atomicAdd(&cursor[b], 1);
    bucket[pos] = a;
  }
}

// ---------------- feature init ----------------

__global__ __launch_bounds__(256) void k_atom_init(const int* xa, const float* e0,
                                                   const float* e1, const float* e2, float* x) {
  int idx = blockIdx.x * 256 + threadIdx.x;  // float4 index
  if (idx >= NA * 16) return;
  int a = idx >> 4, q = idx & 15;
  int f0 = xa[a * 3], f1 = xa[a * 3 + 1], f2 = xa[a * 3 + 2];
  float4 v0 = ((const float4*)e0)[f0 * 16 + q];
  float4 v1 = ((const float4*)e1)[f1 * 16 + q];
  float4 v2 = ((const float4*)e2)[f2 * 16 + q];
  float4 o;
  o.x = v0.x + v1.x + v2.x; o.y = v0.y + v1.y + v2.y;
  o.z = v0.z + v1.z + v2.z; o.w = v0.w + v1.w + v2.w;
  ((float4*)x)[idx] = o;
}

// snapshot: xh = f16(x)
__global__ __launch_bounds__(256) void k_snap(const float* x, f16* xh) {
  int idx = blockIdx.x * 256 + threadIdx.x;
  if (idx >= NA * 16) return;
  float4 v = ((const float4*)x)[idx];
  half4 h = {(f16)v.x, (f16)v.y, (f16)v.z, (f16)v.w};
  ((half4*)xh)[idx] = h;
}

struct PInit {
  __half* dst[5];
  const int* vals[5];
  const float* tab[5];
  int start8[5];  // cumulative half8-chunk starts
  int total8;
};

__global__ __launch_bounds__(256) void k_path_init(PInit pp) {
  for (int g = blockIdx.x * 256 + threadIdx.x; g < pp.total8; g += gridDim.x * 256) {
    int m = 0;
#pragma unroll
    for (int i = 1; i < 5; i++) if (g >= pp.start8[i]) m = i;
    int lc = g - pp.start8[m];
    int e = lc >> 3, q = lc & 7;
    int v = pp.vals[m][e];
    const float* src = pp.tab[m] + v * 64 + q * 8;
    H8 o;
#pragma unroll
    for (int j = 0; j < 8; j++) o.h[j] = __float2half(src[j]);
    ((uint4*)pp.dst[m])[lc] = o.u;
  }
}

// ---------------- prepack conv kernels to fp16 MFMA-B layout ----------------

__global__ __launch_bounds__(256) void k_prepB(const float* pK, const float* cK, f16* Bp) {
  int tid = blockIdx.x * 256 + threadIdx.x;
  if (tid >= 10 * 12288) return;
  int set = tid / 12288, pos = tid % 12288;
  int j = pos & 7, lane = (pos >> 3) & 63, kcnt = pos >> 9;
  int kc = kcnt % 6, nt = kcnt / 6;
  int k = kc * 32 + ((lane >> 4) << 3) + j;
  int n = (nt << 4) + (lane & 15);
  int w = k >> 6, ji = k & 63;
  const float* K = (set < 6) ? (pK + set * 3 * 4096) : (cK + (set - 6) * 3 * 4096);
  float v = K[w * 4096 + ji * 64 + n];
  if (set >= 6) v = 0.5f * (v + K[(2 - w) * 4096 + ji * 64 + n]);
  Bp[tid] = (f16)v;
}

// ---------------- prepack 64x64 weights to fp16 MFMA-B layout ----------------
// sets 0..5 pW_p2a, 6..9 cW_p2a, 10..15 pW_a2p, 16..19 cW_a2p

__global__ __launch_bounds__(256) void k_prepW(const float* pW, const float* cW,
                                               const float* pWa, const float* cWa, f16* Wp) {
  int tid = blockIdx.x * 256 + threadIdx.x;
  if (tid >= 20 * 4096) return;
  int set = tid >> 12, pos = tid & 4095;
  int j = pos & 7, lane = (pos >> 3) & 63, ntkc = pos >> 9;
  int kc = ntkc & 1, nt = ntkc >> 1;
  int k = kc * 32 + ((lane >> 4) << 3) + j;
  int n = (nt << 4) + (lane & 15);
  const float* W;
  if (set < 6) W = pW + set * 4096;
  else if (set < 10) W = cW + (set - 6) * 4096;
  else if (set < 16) W = pWa + (set - 10) * 4096;
  else W = cWa + (set - 16) * 4096;
  Wp[tid] = (f16)W[k * 64 + n];
}

// ---------------- fused a2p+conv per map-group (batched segs, no atomics) ----------------
//   t = xp_old + relu(gather(xh) @ Wa + ba)
//   xp_new = t + relu(conv3(t) @ K + Kb)

struct FusedParams {
  const f16* xh;
  const int* gidx[3];
  __half* xp[3];
  const f16* Wa[3];
  const float* ba[3];
  const f16* Bp[3];
  const float* Kb[3];
  int k[3];
  int P[3];
  int ppb[3];
  int blk_start[3];
  int nseg;
  int cyclic;
};

__global__ __launch_bounds__(256) void k_fused(FusedParams p) {
  __shared__ uint4 CfU[1584];   // 25.3KB: a2p A-frags (<=12.3KB), then fp32 C tile [96xCLD2]
  __shared__ uint4 xn4[873];    // 14KB: xnew f16, 97 rows x 9 uint4 (row 96 = zeros)
  __shared__ float bl[64], kbl[64];
  __shared__ int ridx[96];
  float* Cf = (float*)CfU;
  uint4* Af = CfU;
  int bid = blockIdx.x;
  int seg = 0;
#pragma unroll
  for (int i = 1; i < 3; i++) if (i < p.nseg && bid >= p.blk_start[i]) seg = i;
  int kk = p.k[seg], ppb = p.ppb[seg], P = p.P[seg];
  int cyc = p.cyclic;
  int t = threadIdx.x;
  int p0 = (bid - p.blk_start[seg]) * ppb;
  int np = min(ppb, P - p0);
  int R = np * kk;      // multiple of 16 (16..96)
  int mtb = R >> 4;
  long ebase = (long)p0 * kk;
  if (t < 64) { bl[t] = p.ba[seg][t]; kbl[t] = p.Kb[seg][t]; }
  if (t < 9) { uint4 z; z.x = z.y = z.z = z.w = 0; xn4[96 * 9 + t] = z; }
  if (t < R) ridx[t] = p.gidx[seg][ebase + t];
  __syncthreads();
  // ---- a2p A-frag fill, dest-major (conflict-free LDS writes), f16 gather
  const uint4* xh4 = (const uint4*)p.xh;
  int nunits = mtb * 128;
  for (int j = t; j < nunits; j += 256) {
    int frag = j >> 6, lb = j & 63;
    int row = ((frag >> 1) << 4) + (lb & 15);
    int ch = ((frag & 1) << 2) + (lb >> 4);
    Af[j] = xh4[(long)ridx[row] * 8 + ch];
  }
  __syncthreads();
  int lane = t & 63, wid = t >> 6;
  int wave_n = wid & 1, wave_m = wid >> 1;
  int mtA = (mtb + 1) >> 1;
  int m0 = wave_m ? mtA : 0;
  int mcnt = wave_m ? (mtb - mtA) : mtA;  // <= 3
  // ---- a2p MFMA
  f32x4 acc1[3][2];
#pragma unroll
  for (int i = 0; i < 3; i++)
#pragma unroll
    for (int jn = 0; jn < 2; jn++) { f32x4 z = {0.f, 0.f, 0.f, 0.f}; acc1[i][jn] = z; }
  const uint4* Wau = (const uint4*)p.Wa[seg];
#pragma unroll
  for (int kc = 0; kc < 2; kc++) {
    HU a[3], b[2];
#pragma unroll
    for (int jn = 0; jn < 2; jn++)
      b[jn].u = Wau[(((wave_n * 2 + jn) << 1) + kc) * 64 + lane];
#pragma unroll
    for (int i = 0; i < 3; i++)
      if (i < mcnt) a[i].u = Af[(((m0 + i) << 1) + kc) * 64 + lane];
#pragma unroll
    for (int i = 0; i < 3; i++)
      if (i < mcnt) {
#pragma unroll
        for (int jn = 0; jn < 2; jn++)
          acc1[i][jn] = __builtin_amdgcn_mfma_f32_16x16x32_f16(a[i].h, b[jn].h, acc1[i][jn], 0, 0, 0);
      }
  }
  __syncthreads();  // Af reads done; Cf may overwrite
  // ---- a2p epilogue -> Cf
#pragma unroll
  for (int i = 0; i < 3; i++) {
    if (i >= mcnt) continue;
#pragma unroll
    for (int jn = 0; jn < 2; jn++) {
      int n = ((wave_n * 2 + jn) << 4) + (lane & 15);
      float bv = bl[n];
      int rb = ((m0 + i) << 4) + ((lane >> 4) << 2);
#pragma unroll
      for (int reg = 0; reg < 4; reg++) {
        float v = acc1[i][jn][reg] + bv;
        Cf[(rb + reg) * CLD2 + n] = v > 0.f ? v : 0.f;
      }
    }
  }
  __syncthreads();
  // ---- t = xp_old + relu(...) -> xnew (LDS, stride-9: conflict-free)
  uint4* xg = (uint4*)(p.xp[seg] + (long)ebase * 64);
  for (int idx = t; idx < R * 8; idx += 256) {
    int row = idx >> 3, ch = idx & 7;
    HU res; res.u = xg[idx];
    const float* c = &Cf[row * CLD2 + ch * 8];
    HU o;
#pragma unroll
    for (int j = 0; j < 8; j++) o.s[j] = (f16)((float)res.s[j] + c[j]);
    xn4[row * 9 + ch] = o.u;
  }
  __syncthreads();
  // ---- conv MFMA: A-frags from xnew with shifted rows
  f32x4 acc2[3][2];
#pragma unroll
  for (int i = 0; i < 3; i++)
#pragma unroll
    for (int jn = 0; jn < 2; jn++) { f32x4 z = {0.f, 0.f, 0.f, 0.f}; acc2[i][jn] = z; }
  int rdw[3][3];
#pragma unroll
  for (int i = 0; i < 3; i++) {
    if (i >= mcnt) continue;
    int mr = ((m0 + i) << 4) + (lane & 15);
    int sm = mr % kk;
    rdw[i][1] = mr;
    rdw[i][0] = (sm >= 1) ? mr - 1 : (cyc ? mr + kk - 1 : 96);
    rdw[i][2] = (sm + 1 < kk) ? mr + 1 : (cyc ? mr + 1 - kk : 96);
  }
  const uint4* Bg = (const uint4*)p.Bp[seg];
  for (int kc = 0; kc < 6; kc++) {
    int w = kc >> 1;
    int chunk = ((kc & 1) << 2) + (lane >> 4);
    HU a[3], b[2];
#pragma unroll
    for (int jn = 0; jn < 2; jn++)
      b[jn].u = Bg[((wave_n * 2 + jn) * 6 + kc) * 64 + lane];
#pragma unroll
    for (int i = 0; i < 3; i++)
      if (i < mcnt) a[i].u = xn4[rdw[i][w] * 9 + chunk];
#pragma unroll
    for (int i = 0; i < 3; i++)
      if (i < mcnt) {
#pragma unroll
        for (int jn = 0; jn < 2; jn++)
          acc2[i][jn] = __builtin_amdgcn_mfma_f32_16x16x32_f16(a[i].h, b[jn].h, acc2[i][jn], 0, 0, 0);
      }
  }
  __syncthreads();  // xnew-combine Cf reads done; Cf overwrite OK
  // ---- conv epilogue -> Cf
#pragma unroll
  for (int i = 0; i < 3; i++) {
    if (i >= mcnt) continue;
#pragma unroll
    for (int jn = 0; jn < 2; jn++) {
      int n = ((wave_n * 2 + jn) << 4) + (lane & 15);
      float bv = kbl[n];
      int rb = ((m0 + i) << 4) + ((lane >> 4) << 2);
#pragma unroll
      for (int reg = 0; reg < 4; reg++) {
        float v = acc2[i][jn][reg] + bv;
        Cf[(rb + reg) * CLD2 + n] = v > 0.f ? v : 0.f;
      }
    }
  }
  __syncthreads();
  // ---- final: xp_new = xnew + relu-conv, single coalesced global write
  for (int idx = t; idx < R * 8; idx += 256) {
    int row = idx >> 3, ch = idx & 7;
    HU res; res.u = xn4[row * 9 + ch];
    const float* c = &Cf[row * CLD2 + ch * 8];
    HU o;
#pragma unroll
    for (int j = 0; j < 8; j++) o.s[j] = (f16)((float)res.s[j] + c[j]);
    xg[idx] = o.u;
  }
}

// ---------------- p2a scatter: acc[row[e]] += xp[e] (packed f16 global atomics) ----------

__global__ __launch_bounds__(256) void k_scatter(const f16* xp, const int* row,
                                                 __half2* acc, int E) {
  int gw = (blockIdx.x * 256 + threadIdx.x) >> 6;
  int half = (threadIdx.x >> 5) & 1;
  int l = threadIdx.x & 31;
  int nw = (gridDim.x * 256) >> 6;
  const unsigned int* xpu = (const unsigned int*)xp;
  for (int e0 = gw * 8; e0 < E; e0 += nw * 8) {
    int e[4]; unsigned int v[4]; int a[4];
#pragma unroll
    for (int u = 0; u < 4; u++) e[u] = e0 + 2 * u + half;
#pragma unroll
    for (int u = 0; u < 4; u++) v[u] = xpu[(long)e[u] * 32 + l];
#pragma unroll
    for (int u = 0; u < 4; u++) a[u] = row[e[u]];
#pragma unroll
    for (int u = 0; u < 4; u++) {
      __half2 hv = *(__half2*)&v[u];
      pk_atomic_add(&acc[(long)a[u] * 32 + l], hv);
    }
  }
}

// ---------------- p2a apply: x += relu(acc/cnt @ W + b); self-zeroes f16 acc ----------------

__global__ __launch_bounds__(256) void k_apply(f16* acc, const int* cnt, const f16* Wp,
                                               const float* bias, float* x) {
  __shared__ float mean[64 * MLD];  // 17.4KB
  __shared__ uint4 Af[512];         // 8KB fp16 A-frags
  __shared__ float invl[64];
  __shared__ float bl[64];
  int t = threadIdx.x;
  int a0 = blockIdx.x * 64;
  if (t < 64) {
    int cb = cnt[a0 + t];
    invl[t] = 1.f / (float)(cb > 0 ? cb : 1);
    bl[t] = bias[t];
  }
  uint4* acc4 = (uint4*)acc;  // 8 halves per uint4; 64 rows x 8 = 512 per tile
#pragma unroll
  for (int i = 0; i < 2; i++) {
    int idx = t + 256 * i;
    int r = idx >> 3, q = idx & 7;
    HU v; v.u = acc4[(long)a0 * 8 + idx];
    uint4 z4; z4.x = z4.y = z4.z = z4.w = 0;
    acc4[(long)a0 * 8 + idx] = z4;  // ready for next map
    float* mr = &mean[r * MLD + q * 8];
#pragma unroll
    for (int j = 0; j < 8; j++) mr[j] = (float)v.s[j];
  }
  __syncthreads();
  // dest-major A-frag fill (conflict-free LDS writes)
#pragma unroll
  for (int i = 0; i < 2; i++) {
    int j = t + 256 * i;
    int frag = j >> 6, lb = j & 63;
    int row = ((frag >> 1) << 4) + (lb & 15);
    int ch = ((frag & 1) << 2) + (lb >> 4);
    float inv = invl[row];
    const float* mr = &mean[row * MLD + ch * 8];
    HU o;
#pragma unroll
    for (int jj = 0; jj < 8; jj++) o.h[jj] = (f16)(mr[jj] * inv);
    Af[j] = o.u;
  }
  __syncthreads();
  int lane = t & 63, wid = t >> 6;
  HU af0, af1;
  af0.u = Af[((wid << 1) + 0) * 64 + lane];
  af1.u = Af[((wid << 1) + 1) * 64 + lane];
  const uint4* Wu = (const uint4*)Wp;
  int rowb = a0 + wid * 16 + ((lane >> 4) << 2);
#pragma unroll
  for (int nt = 0; nt < 4; nt++) {
    HU b0, b1;
    b0.u = Wu[((nt << 1) + 0) * 64 + lane];
    b1.u = Wu[((nt << 1) + 1) * 64 + lane];
    f32x4 z = {0.f, 0.f, 0.f, 0.f};
    z = __builtin_amdgcn_mfma_f32_16x16x32_f16(af0.h, b0.h, z, 0, 0, 0);
    z = __builtin_amdgcn_mfma_f32_16x16x32_f16(af1.h, b1.h, z, 0, 0, 0);
    int n = nt * 16 + (lane & 15);
    float bv = bl[n];
#pragma unroll
    for (int r = 0; r < 4; r++) {
      int atom = rowb + r;
      if (atom < NA) {
        float vv = z[r] + bv;
        vv = vv > 0.f ? vv : 0.f;
        x[(long)atom * 64 + n] += vv;
      }
    }
  }
}

// ---------------- batch mean: g1[b] = mean(x[a]) over CSR bucket ----------------

__global__ __launch_bounds__(256) void k_meanscatter(const float* src, const int* bucket,
                                                     const int* basea, const int* cnta,
                                                     float* dst, int nseg) {
  int wid = (blockIdx.x * 256 + threadIdx.x) >> 6;
  int lane = threadIdx.x & 63;
  if (wid >= nseg) return;
  int b0 = basea[wid], cnt = cnta[wid];
  float s = 0.f;
  for (int i = 0; i < cnt; i++) {
    int e = bucket[b0 + i];
    s += src[(long)e * 64 + lane];
  }
  dst[(long)wid * 64 + lane] = s / (float)(cnt > 0 ? cnt : 1);
}

// ---------------- head gemm: g2 = relu(g1 @ W + b) ----------------

__global__ __launch_bounds__(256) void k_head(const float* g1, const float* W,
                                              const float* bias, float* g2) {
  __shared__ float Wl[4096];
  __shared__ float inl[32 * 64];
  __shared__ float bl[64];
  int t = threadIdx.x;
  int brow = blockIdx.x * 32;
#pragma unroll
  for (int i = 0; i < 4; i++) ((float4*)Wl)[t + 256 * i] = ((const float4*)W)[t + 256 * i];
  if (t < 64) bl[t] = bias[t];
  __syncthreads();
#pragma unroll
  for (int i = 0; i < 2; i++) {
    int idx = t + 256 * i;
    int r = idx >> 4, q = idx & 15;
    ((float4*)inl)[idx] = ((const float4*)(g1 + (long)(brow + r) * 64))[q];
  }
  __syncthreads();
  int c = t & 63, rq = t >> 6;
  float acc[8];
#pragma unroll
  for (int i = 0; i < 8; i++) acc[i] = 0.f;
  for (int j = 0; j < 64; j += 4) {
    float w0 = Wl[(j + 0) * 64 + c], w1 = Wl[(j + 1) * 64 + c];
    float w2 = Wl[(j + 2) * 64 + c], w3 = Wl[(j + 3) * 64 + c];
#pragma unroll
    for (int i = 0; i < 8; i++) {
      int r = rq * 8 + i;
      float4 v = *(const float4*)&inl[r * 64 + j];
      acc[i] += v.x * w0 + v.y * w1 + v.z * w2 + v.w * w3;
    }
  }
#pragma unroll
  for (int i = 0; i < 8; i++) {
    long r = brow + rq * 8 + i;
    float v = acc[i] + bl[c];
    g2[r * 64 + c] = v > 0.f ? v : 0.f;
  }
}

__global__ __launch_bounds__(256) void k_final(const float* g2, const float* linW,
                                               const float* linb, float* out) {
  int wid = (blockIdx.x * 256 + threadIdx.x) >> 6;
  int lane = threadIdx.x & 63;
  if (wid >= NBATCH) return;
  float v = g2[(long)wid * 64 + lane] * linW[lane];
  for (int o = 32; o > 0; o >>= 1) v += __shfl_down(v, o, 64);
  if (lane == 0) out[wid] = v + linb[0];
}

__global__ __launch_bounds__(256) void k_zero_out(float* out, int n) {
  for (int i = blockIdx.x * 256 + threadIdx.x; i < n; i += gridDim.x * 256) out[i] = 0.f;
}

// ---------------- launcher ----------------

extern "C" void kernel_launch(void* const* d_in, const int* in_sizes, int n_in,
                              void* d_out, int out_size, void* d_ws, size_t ws_size,
                              hipStream_t stream) {
  (void)in_sizes; (void)n_in;

  const int* x_atom = (const int*)d_in[0];
  const int* vals[5] = {(const int*)d_in[1], (const int*)d_in[4], (const int*)d_in[7],
                        (const int*)d_in[10], (const int*)d_in[13]};
  const int* rowm[5] = {(const int*)d_in[2], (const int*)d_in[5], (const int*)d_in[8],
                        (const int*)d_in[11], (const int*)d_in[14]};
  const int* batch = (const int*)d_in[16];
  const float* aemb0 = (const float*)d_in[17];
  const float* aemb1 = (const float*)d_in[18];
  const float* aemb2 = (const float*)d_in[19];
  const float* path_emb = (const float*)d_in[20];
  const float* cycle_emb = (const float*)d_in[21];
  const float* pW_a2p = (const float*)d_in[22];
  const float* pb_a2p = (const float*)d_in[23];
  const float* pW_p2a = (const float*)d_in[24];
  const float* pb_p2a = (const float*)d_in[25];
  const float* pK = (const float*)d_in[26];
  const float* pKb = (const float*)d_in[27];
  const float* cW_a2p = (const float*)d_in[28];
  const float* cb_a2p = (const float*)d_in[29];
  const float* cW_p2a = (const float*)d_in[30];
  const float* cb_p2a = (const float*)d_in[31];
  const float* cK = (const float*)d_in[32];
  const float* cKb = (const float*)d_in[33];
  const float* alW = (const float*)d_in[34];
  const float* alb = (const float*)d_in[35];
  const float* linW = (const float*)d_in[36];
  const float* linb = (const float*)d_in[37];

  static const int Em[5] = {300000, 400000, 500000, 200000, 240000};
  static const int Km[5] = {3, 4, 5, 5, 6};
  static const int Ppb[5] = {32, 24, 16, 16, 16};
  const int CNT_N = 5 * 100000 + NBATCH;  // 504096
  const int ACC_ROWS = 100032;            // padded to apply grid (1563*64)

  char* ws = (char*)d_ws;
  size_t off = 0;
  auto alloc = [&](size_t nbytes) -> char* {
    char* p = ws + off;
    off = (off + nbytes + 255) & ~(size_t)255;
    return p;
  };
  float* x = (float*)alloc((size_t)NA * 64 * 4);
  f16* xh = (f16*)alloc((size_t)NA * 64 * 2);  // f16 snapshot for group-local gathers
  __half* xp[5];
  for (int m = 0; m < 5; m++) xp[m] = (__half*)alloc((size_t)Em[m] * 64 * 2);
  f16* acc = (f16*)alloc((size_t)ACC_ROWS * 64 * 2);  // f16 accumulator
  float* g1 = (float*)alloc((size_t)NBATCH * 64 * 4);
  float* g2 = (float*)alloc((size_t)NBATCH * 64 * 4);
  int* cnt = (int*)alloc((size_t)CNT_N * 4);
  int* basea_b = (int*)alloc((size_t)(NBATCH + 1) * 4);
  int* cursor_b = (int*)alloc((size_t)NBATCH * 4);
  int* bucket = (int*)alloc((size_t)NA * 4);
  f16* Bp = (f16*)alloc((size_t)10 * 12288 * 2);  // prepacked conv kernels
  f16* Wpk = (f16*)alloc((size_t)20 * 4096 * 2);  // prepacked p2a+a2p weights

  if (ws_size < off) {  // workspace too small: emit readable failure, not a fault
    k_zero_out<<<16, 256, 0, stream>>>((float*)d_out, out_size);
    return;
  }

  // ---- counts (all maps + batch) and batch CSR
  MapsParams mp;
  {
    int s = 0;
    for (int m = 0; m < 5; m++) {
      mp.row[m] = rowm[m]; mp.cnt_off[m] = m * 100000;
      mp.start[m] = s; s += Em[m];
    }
    mp.row[5] = batch; mp.cnt_off[5] = 500000; mp.start[5] = s;
    mp.total = s + NA;
  }
  (void)hipMemsetAsync(cnt, 0, (size_t)CNT_N * 4, stream);
  (void)hipMemsetAsync(acc, 0, (size_t)ACC_ROWS * 64 * 2, stream);
  k_count<<<2048, 256, 0, stream>>>(mp, cnt);
  k_scan_batch<<<1, 256, 0, stream>>>(cnt + 500000, basea_b);
  (void)hipMemcpyAsync(cursor_b, basea_b, (size_t)NBATCH * 4, hipMemcpyDeviceToDevice, stream);
  k_fill_batch<<<128, 256, 0, stream>>>(batch, cursor_b, bucket);

  // ---- prepack weights + feature init
  k_prepB<<<480, 256, 0, stream>>>(pK, cK, Bp);
  k_prepW<<<320, 256, 0, stream>>>(pW_p2a, cW_p2a, pW_a2p, cW_a2p, Wpk);
  k_atom_init<<<NA * 16 / 256, 256, 0, stream>>>(x_atom, aemb0, aemb1, aemb2, x);
  {
    PInit pp;
    int s8 = 0;
    for (int m = 0; m < 5; m++) {
      pp.dst[m] = xp[m];
      pp.vals[m] = vals[m];
      pp.tab[m] = (m < 3) ? (path_emb + m * 6 * 64) : (cycle_emb + (m - 3) * 4 * 64);
      pp.start8[m] = s8;
      s8 += Em[m] * 8;
    }
    pp.total8 = s8;
    k_path_init<<<8192, 256, 0, stream>>>(pp);
  }

  int apply_blocks = ACC_ROWS / 64;  // 1563
  int snap_blocks = NA * 16 / 256;   // 6250

  // ---- layers
  for (int l = 0; l < 2; l++) {
    // === paths group (maps 0..2), non-cyclic
    k_snap<<<snap_blocks, 256, 0, stream>>>(x, xh);
    {
      FusedParams fp{};
      fp.nseg = 3; fp.cyclic = 0; fp.xh = xh;
      int bs = 0;
      for (int m = 0; m < 3; m++) {
        fp.gidx[m] = rowm[m]; fp.xp[m] = xp[m];
        fp.Wa[m] = Wpk + (size_t)(10 + l * 3 + m) * 4096;
        fp.ba[m] = pb_a2p + (l * 3 + m) * 64;
        fp.Bp[m] = Bp + (size_t)(l * 3 + m) * 12288;
        fp.Kb[m] = pKb + (l * 3 + m) * 64;
        fp.k[m] = Km[m]; fp.P[m] = Em[m] / Km[m]; fp.ppb[m] = Ppb[m];
        fp.blk_start[m] = bs;
        bs += (fp.P[m] + fp.ppb[m] - 1) / fp.ppb[m];
      }
      k_fused<<<bs, 256, 0, stream>>>(fp);

      for (int m = 0; m < 3; m++) {
        k_scatter<<<1024, 256, 0, stream>>>((const f16*)xp[m], rowm[m], (__half2*)acc, Em[m]);
        k_apply<<<apply_blocks, 256, 0, stream>>>(acc, cnt + m * 100000,
                                                  Wpk + (size_t)(l * 3 + m) * 4096,
                                                  pb_p2a + (l * 3 + m) * 64, x);
      }
    }
    // === cycles group (maps 3..4), cyclic
    k_snap<<<snap_blocks, 256, 0, stream>>>(x, xh);
    {
      FusedParams fp{};
      fp.nseg = 2; fp.cyclic = 1; fp.xh = xh;
      int bs = 0;
      for (int m = 3; m < 5; m++) {
        int i = m - 3;
        fp.gidx[i] = rowm[m]; fp.xp[i] = xp[m];
        fp.Wa[i] = Wpk + (size_t)(16 + l * 2 + i) * 4096;
        fp.ba[i] = cb_a2p + (l * 2 + i) * 64;
        fp.Bp[i] = Bp + (size_t)(6 + l * 2 + i) * 12288;
        fp.Kb[i] = cKb + (l * 2 + i) * 64;
        fp.k[i] = Km[m]; fp.P[i] = Em[m] / Km[m]; fp.ppb[i] = Ppb[m];
        fp.blk_start[i] = bs;
        bs += (fp.P[i] + fp.ppb[i] - 1) / fp.ppb[i];
      }
      k_fused<<<bs, 256, 0, stream>>>(fp);

      for (int m = 3; m < 5; m++) {
        int i = m - 3;
        k_scatter<<<1024, 256, 0, stream>>>((const f16*)xp[m], rowm[m], (__half2*)acc, Em[m]);
        k_apply<<<apply_blocks, 256, 0, stream>>>(acc, cnt + m * 100000,
                                                  Wpk + (size_t)(6 + l * 2 + i) * 4096,
                                                  cb_p2a + (l * 2 + i) * 64, x);
      }
    }
  }

  // ---- head
  k_meanscatter<<<NBATCH / 4, 256, 0, stream>>>(x, bucket, basea_b, cnt + 500000,
                                                g1, NBATCH);
  k_head<<<NBATCH / 32, 256, 0, stream>>>(g1, alW, alb, g2);
  k_final<<<NBATCH / 4, 256, 0, stream>>>(g2, linW, linb, (float*)d_out);
}

// Round 15
// 1217.123 us; speedup vs baseline: 1.7258x; 1.0644x over previous
//
#include <hip/hip_runtime.h>
#include <hip/hip_fp16.h>

#define NA 100000
#define NBATCH 4096
#define MLD 68
#define CLD2 66

typedef _Float16 f16;
typedef f16 half8 __attribute__((ext_vector_type(8)));
typedef f16 half4 __attribute__((ext_vector_type(4)));
typedef float f32x4 __attribute__((ext_vector_type(4)));
union H8 { uint4 u; __half h[8]; };
union HU { uint4 u; half8 h; f16 s[8]; };

// packed f16 atomic add: HIP has no atomicAdd(__half2*); use the HW pk_add_f16 path.
__device__ inline void pk_atomic_add(__half2* addr, __half2 v) {
#if __has_builtin(__builtin_amdgcn_flat_atomic_fadd_v2f16)
  typedef _Float16 hv2 __attribute__((ext_vector_type(2)));
  __builtin_amdgcn_flat_atomic_fadd_v2f16((hv2*)addr, *(hv2*)&v);
#else
  unsafeAtomicAdd(addr, v);
#endif
}

// ---------------- counts (all 5 maps + batch) ----------------

struct MapsParams {
  const int* row[6];
  int cnt_off[6];
  int start[6];
  int total;
};

__global__ __launch_bounds__(256) void k_count(MapsParams mp, int* cnt) {
  for (int g = blockIdx.x * 256 + threadIdx.x; g < mp.total; g += gridDim.x * 256) {
    int m = 0;
#pragma unroll
    for (int i = 1; i < 6; i++) if (g >= mp.start[i]) m = i;
    int e = g - mp.start[m];
    atomicAdd(&cnt[mp.cnt_off[m] + mp.row[m][e]], 1);
  }
}

__global__ __launch_bounds__(256) void k_scan_batch(const int* cntb, int* basea) {
  __shared__ int s[256];
  int t = threadIdx.x;
  int carry = 0;
  for (int c0 = 0; c0 < NBATCH; c0 += 256) {
    int v = cntb[c0 + t];
    s[t] = v;
    __syncthreads();
    for (int d = 1; d < 256; d <<= 1) {
      int x = (t >= d) ? s[t - d] : 0;
      __syncthreads();
      s[t] += x;
      __syncthreads();
    }
    basea[c0 + t] = s[t] - v + carry;
    int tot = s[255];
    __syncthreads();
    carry += tot;
  }
}

__global__ __launch_bounds__(256) void k_fill_batch(const int* batch, int* cursor, int* bucket) {
  for (int a = blockIdx.x * 256 + threadIdx.x; a < NA; a += gridDim.x * 256) {
    int b = batch[a];
    int pos = atomicAdd(&cursor[b], 1);
    bucket[pos] = a;
  }
}

// ---------------- feature init (x stored f16) ----------------

__global__ __launch_bounds__(256) void k_atom_init(const int* xa, const float* e0,
                                                   const float* e1, const float* e2, f16* x) {
  int idx = blockIdx.x * 256 + threadIdx.x;  // float4-group index
  if (idx >= NA * 16) return;
  int a = idx >> 4, q = idx & 15;
  int f0 = xa[a * 3], f1 = xa[a * 3 + 1], f2 = xa[a * 3 + 2];
  float4 v0 = ((const float4*)e0)[f0 * 16 + q];
  float4 v1 = ((const float4*)e1)[f1 * 16 + q];
  float4 v2 = ((const float4*)e2)[f2 * 16 + q];
  half4 h = {(f16)(v0.x + v1.x + v2.x), (f16)(v0.y + v1.y + v2.y),
             (f16)(v0.z + v1.z + v2.z), (f16)(v0.w + v1.w + v2.w)};
  ((half4*)x)[idx] = h;
}

struct PInit {
  __half* dst[5];
  const int* vals[5];
  const float* tab[5];
  int start8[5];  // cumulative half8-chunk starts
  int total8;
};

__global__ __launch_bounds__(256) void k_path_init(PInit pp) {
  for (int g = blockIdx.x * 256 + threadIdx.x; g < pp.total8; g += gridDim.x * 256) {
    int m = 0;
#pragma unroll
    for (int i = 1; i < 5; i++) if (g >= pp.start8[i]) m = i;
    int lc = g - pp.start8[m];
    int e = lc >> 3, q = lc & 7;
    int v = pp.vals[m][e];
    const float* src = pp.tab[m] + v * 64 + q * 8;
    H8 o;
#pragma unroll
    for (int j = 0; j < 8; j++) o.h[j] = __float2half(src[j]);
    ((uint4*)pp.dst[m])[lc] = o.u;
  }
}

// ---------------- prepack conv kernels to fp16 MFMA-B layout ----------------

__global__ __launch_bounds__(256) void k_prepB(const float* pK, const float* cK, f16* Bp) {
  int tid = blockIdx.x * 256 + threadIdx.x;
  if (tid >= 10 * 12288) return;
  int set = tid / 12288, pos = tid % 12288;
  int j = pos & 7, lane = (pos >> 3) & 63, kcnt = pos >> 9;
  int kc = kcnt % 6, nt = kcnt / 6;
  int k = kc * 32 + ((lane >> 4) << 3) + j;
  int n = (nt << 4) + (lane & 15);
  int w = k >> 6, ji = k & 63;
  const float* K = (set < 6) ? (pK + set * 3 * 4096) : (cK + (set - 6) * 3 * 4096);
  float v = K[w * 4096 + ji * 64 + n];
  if (set >= 6) v = 0.5f * (v + K[(2 - w) * 4096 + ji * 64 + n]);
  Bp[tid] = (f16)v;
}

// ---------------- prepack 64x64 weights to fp16 MFMA-B layout ----------------
// sets 0..5 pW_p2a, 6..9 cW_p2a, 10..15 pW_a2p, 16..19 cW_a2p

__global__ __launch_bounds__(256) void k_prepW(const float* pW, const float* cW,
                                               const float* pWa, const float* cWa, f16* Wp) {
  int tid = blockIdx.x * 256 + threadIdx.x;
  if (tid >= 20 * 4096) return;
  int set = tid >> 12, pos = tid & 4095;
  int j = pos & 7, lane = (pos >> 3) & 63, ntkc = pos >> 9;
  int kc = ntkc & 1, nt = ntkc >> 1;
  int k = kc * 32 + ((lane >> 4) << 3) + j;
  int n = (nt << 4) + (lane & 15);
  const float* W;
  if (set < 6) W = pW + set * 4096;
  else if (set < 10) W = cW + (set - 6) * 4096;
  else if (set < 16) W = pWa + (set - 10) * 4096;
  else W = cWa + (set - 16) * 4096;
  Wp[tid] = (f16)W[k * 64 + n];
}

// ---------------- fused a2p+conv per map-group (batched segs) ----------------
//   t = xp_old + relu(gather(xh) @ Wa + ba)
//   xp_new = t + relu(conv3(t) @ K + Kb)

struct FusedParams {
  const f16* xh;
  const int* gidx[3];
  __half* xp[3];
  const f16* Wa[3];
  const float* ba[3];
  const f16* Bp[3];
  const float* Kb[3];
  int k[3];
  int P[3];
  int ppb[3];
  int blk_start[3];
  int nseg;
  int cyclic;
};

__global__ __launch_bounds__(256) void k_fused(FusedParams p) {
  __shared__ uint4 CfU[1584];   // 25.3KB: a2p A-frags (<=12.3KB), then fp32 C tile [96xCLD2]
  __shared__ uint4 xn4[873];    // 14KB: xnew f16, 97 rows x 9 uint4 (row 96 = zeros)
  __shared__ float bl[64], kbl[64];
  __shared__ int ridx[96];
  float* Cf = (float*)CfU;
  uint4* Af = CfU;
  int bid = blockIdx.x;
  int seg = 0;
#pragma unroll
  for (int i = 1; i < 3; i++) if (i < p.nseg && bid >= p.blk_start[i]) seg = i;
  int kk = p.k[seg], ppb = p.ppb[seg], P = p.P[seg];
  int cyc = p.cyclic;
  int t = threadIdx.x;
  int p0 = (bid - p.blk_start[seg]) * ppb;
  int np = min(ppb, P - p0);
  int R = np * kk;      // multiple of 16 (16..96)
  int mtb = R >> 4;
  long ebase = (long)p0 * kk;
  if (t < 64) { bl[t] = p.ba[seg][t]; kbl[t] = p.Kb[seg][t]; }
  if (t < 9) { uint4 z; z.x = z.y = z.z = z.w = 0; xn4[96 * 9 + t] = z; }
  if (t < R) ridx[t] = p.gidx[seg][ebase + t];
  __syncthreads();
  // ---- a2p A-frag fill, dest-major (conflict-free LDS writes), f16 gather
  const uint4* xh4 = (const uint4*)p.xh;
  int nunits = mtb * 128;
  for (int j = t; j < nunits; j += 256) {
    int frag = j >> 6, lb = j & 63;
    int row = ((frag >> 1) << 4) + (lb & 15);
    int ch = ((frag & 1) << 2) + (lb >> 4);
    Af[j] = xh4[(long)ridx[row] * 8 + ch];
  }
  __syncthreads();
  int lane = t & 63, wid = t >> 6;
  int wave_n = wid & 1, wave_m = wid >> 1;
  int mtA = (mtb + 1) >> 1;
  int m0 = wave_m ? mtA : 0;
  int mcnt = wave_m ? (mtb - mtA) : mtA;  // <= 3
  // ---- a2p MFMA
  f32x4 acc1[3][2];
#pragma unroll
  for (int i = 0; i < 3; i++)
#pragma unroll
    for (int jn = 0; jn < 2; jn++) { f32x4 z = {0.f, 0.f, 0.f, 0.f}; acc1[i][jn] = z; }
  const uint4* Wau = (const uint4*)p.Wa[seg];
#pragma unroll
  for (int kc = 0; kc < 2; kc++) {
    HU a[3], b[2];
#pragma unroll
    for (int jn = 0; jn < 2; jn++)
      b[jn].u = Wau[(((wave_n * 2 + jn) << 1) + kc) * 64 + lane];
#pragma unroll
    for (int i = 0; i < 3; i++)
      if (i < mcnt) a[i].u = Af[(((m0 + i) << 1) + kc) * 64 + lane];
#pragma unroll
    for (int i = 0; i < 3; i++)
      if (i < mcnt) {
#pragma unroll
        for (int jn = 0; jn < 2; jn++)
          acc1[i][jn] = __builtin_amdgcn_mfma_f32_16x16x32_f16(a[i].h, b[jn].h, acc1[i][jn], 0, 0, 0);
      }
  }
  __syncthreads();  // Af reads done; Cf may overwrite
  // ---- a2p epilogue -> Cf
#pragma unroll
  for (int i = 0; i < 3; i++) {
    if (i >= mcnt) continue;
#pragma unroll
    for (int jn = 0; jn < 2; jn++) {
      int n = ((wave_n * 2 + jn) << 4) + (lane & 15);
      float bv = bl[n];
      int rb = ((m0 + i) << 4) + ((lane >> 4) << 2);
#pragma unroll
      for (int reg = 0; reg < 4; reg++) {
        float v = acc1[i][jn][reg] + bv;
        Cf[(rb + reg) * CLD2 + n] = v > 0.f ? v : 0.f;
      }
    }
  }
  __syncthreads();
  // ---- t = xp_old + relu(...) -> xnew (LDS, stride-9: conflict-free)
  uint4* xg = (uint4*)(p.xp[seg] + (long)ebase * 64);
  for (int idx = t; idx < R * 8; idx += 256) {
    int row = idx >> 3, ch = idx & 7;
    HU res; res.u = xg[idx];
    const float* c = &Cf[row * CLD2 + ch * 8];
    HU o;
#pragma unroll
    for (int j = 0; j < 8; j++) o.s[j] = (f16)((float)res.s[j] + c[j]);
    xn4[row * 9 + ch] = o.u;
  }
  __syncthreads();
  // ---- conv MFMA: A-frags from xnew with shifted rows
  f32x4 acc2[3][2];
#pragma unroll
  for (int i = 0; i < 3; i++)
#pragma unroll
    for (int jn = 0; jn < 2; jn++) { f32x4 z = {0.f, 0.f, 0.f, 0.f}; acc2[i][jn] = z; }
  int rdw[3][3];
#pragma unroll
  for (int i = 0; i < 3; i++) {
    if (i >= mcnt) continue;
    int mr = ((m0 + i) << 4) + (lane & 15);
    int sm = mr % kk;
    rdw[i][1] = mr;
    rdw[i][0] = (sm >= 1) ? mr - 1 : (cyc ? mr + kk - 1 : 96);
    rdw[i][2] = (sm + 1 < kk) ? mr + 1 : (cyc ? mr + 1 - kk : 96);
  }
  const uint4* Bg = (const uint4*)p.Bp[seg];
  for (int kc = 0; kc < 6; kc++) {
    int w = kc >> 1;
    int chunk = ((kc & 1) << 2) + (lane >> 4);
    HU a[3], b[2];
#pragma unroll
    for (int jn = 0; jn < 2; jn++)
      b[jn].u = Bg[((wave_n * 2 + jn) * 6 + kc) * 64 + lane];
#pragma unroll
    for (int i = 0; i < 3; i++)
      if (i < mcnt) a[i].u = xn4[rdw[i][w] * 9 + chunk];
#pragma unroll
    for (int i = 0; i < 3; i++)
      if (i < mcnt) {
#pragma unroll
        for (int jn = 0; jn < 2; jn++)
          acc2[i][jn] = __builtin_amdgcn_mfma_f32_16x16x32_f16(a[i].h, b[jn].h, acc2[i][jn], 0, 0, 0);
      }
  }
  __syncthreads();  // xnew-combine Cf reads done; Cf overwrite OK
  // ---- conv epilogue -> Cf
#pragma unroll
  for (int i = 0; i < 3; i++) {
    if (i >= mcnt) continue;
#pragma unroll
    for (int jn = 0; jn < 2; jn++) {
      int n = ((wave_n * 2 + jn) << 4) + (lane & 15);
      float bv = kbl[n];
      int rb = ((m0 + i) << 4) + ((lane >> 4) << 2);
#pragma unroll
      for (int reg = 0; reg < 4; reg++) {
        float v = acc2[i][jn][reg] + bv;
        Cf[(rb + reg) * CLD2 + n] = v > 0.f ? v : 0.f;
      }
    }
  }
  __syncthreads();
  // ---- final: xp_new = xnew + relu-conv, single coalesced global write
  for (int idx = t; idx < R * 8; idx += 256) {
    int row = idx >> 3, ch = idx & 7;
    HU res; res.u = xn4[row * 9 + ch];
    const float* c = &Cf[row * CLD2 + ch * 8];
    HU o;
#pragma unroll
    for (int j = 0; j < 8; j++) o.s[j] = (f16)((float)res.s[j] + c[j]);
    xg[idx] = o.u;
  }
}

// ---------------- p2a scatter: acc[row[e]] += xp[e] (packed f16 global atomics) ----------

__global__ __launch_bounds__(256) void k_scatter(const f16* xp, const int* row,
                                                 __half2* acc, int E) {
  int gw = (blockIdx.x * 256 + threadIdx.x) >> 6;
  int half = (threadIdx.x >> 5) & 1;
  int l = threadIdx.x & 31;
  int nw = (gridDim.x * 256) >> 6;
  const unsigned int* xpu = (const unsigned int*)xp;
  for (int e0 = gw * 8; e0 < E; e0 += nw * 8) {
    int e[4]; unsigned int v[4]; int a[4];
#pragma unroll
    for (int u = 0; u < 4; u++) e[u] = e0 + 2 * u + half;
#pragma unroll
    for (int u = 0; u < 4; u++) v[u] = xpu[(long)e[u] * 32 + l];
#pragma unroll
    for (int u = 0; u < 4; u++) a[u] = row[e[u]];
#pragma unroll
    for (int u = 0; u < 4; u++) {
      __half2 hv = *(__half2*)&v[u];
      pk_atomic_add(&acc[(long)a[u] * 32 + l], hv);
    }
  }
}

// ---------------- p2a apply: x += relu(acc/cnt @ W + b); x f16; self-zeroes acc -------------

__global__ __launch_bounds__(256) void k_apply(f16* acc, const int* cnt, const f16* Wp,
                                               const float* bias, f16* x) {
  __shared__ float mean[64 * MLD];  // 17.4KB
  __shared__ uint4 Af[512];         // 8KB fp16 A-frags
  __shared__ float invl[64];
  __shared__ float bl[64];
  int t = threadIdx.x;
  int a0 = blockIdx.x * 64;
  if (t < 64) {
    int cb = cnt[a0 + t];
    invl[t] = 1.f / (float)(cb > 0 ? cb : 1);
    bl[t] = bias[t];
  }
  uint4* acc4 = (uint4*)acc;  // 8 halves per uint4; 64 rows x 8 = 512 per tile
#pragma unroll
  for (int i = 0; i < 2; i++) {
    int idx = t + 256 * i;
    int r = idx >> 3, q = idx & 7;
    HU v; v.u = acc4[(long)a0 * 8 + idx];
    uint4 z4; z4.x = z4.y = z4.z = z4.w = 0;
    acc4[(long)a0 * 8 + idx] = z4;  // ready for next map
    float* mr = &mean[r * MLD + q * 8];
#pragma unroll
    for (int j = 0; j < 8; j++) mr[j] = (float)v.s[j];
  }
  __syncthreads();
  // dest-major A-frag fill (conflict-free LDS writes)
#pragma unroll
  for (int i = 0; i < 2; i++) {
    int j = t + 256 * i;
    int frag = j >> 6, lb = j & 63;
    int row = ((frag >> 1) << 4) + (lb & 15);
    int ch = ((frag & 1) << 2) + (lb >> 4);
    float inv = invl[row];
    const float* mr = &mean[row * MLD + ch * 8];
    HU o;
#pragma unroll
    for (int jj = 0; jj < 8; jj++) o.h[jj] = (f16)(mr[jj] * inv);
    Af[j] = o.u;
  }
  __syncthreads();
  int lane = t & 63, wid = t >> 6;
  HU af0, af1;
  af0.u = Af[((wid << 1) + 0) * 64 + lane];
  af1.u = Af[((wid << 1) + 1) * 64 + lane];
  const uint4* Wu = (const uint4*)Wp;
  int rowb = a0 + wid * 16 + ((lane >> 4) << 2);
#pragma unroll
  for (int nt = 0; nt < 4; nt++) {
    HU b0, b1;
    b0.u = Wu[((nt << 1) + 0) * 64 + lane];
    b1.u = Wu[((nt << 1) + 1) * 64 + lane];
    f32x4 z = {0.f, 0.f, 0.f, 0.f};
    z = __builtin_amdgcn_mfma_f32_16x16x32_f16(af0.h, b0.h, z, 0, 0, 0);
    z = __builtin_amdgcn_mfma_f32_16x16x32_f16(af1.h, b1.h, z, 0, 0, 0);
    int n = nt * 16 + (lane & 15);
    float bv = bl[n];
#pragma unroll
    for (int r = 0; r < 4; r++) {
      int atom = rowb + r;
      if (atom < NA) {
        float vv = z[r] + bv;
        vv = vv > 0.f ? vv : 0.f;
        long oi = (long)atom * 64 + n;
        x[oi] = (f16)((float)x[oi] + vv);
      }
    }
  }
}

// ---------------- batch mean over f16 x: g1[b] = mean(x[a]) ----------------

__global__ __launch_bounds__(256) void k_meanscatter(const f16* src, const int* bucket,
                                                     const int* basea, const int* cnta,
                                                     float* dst, int nseg) {
  int wid = (blockIdx.x * 256 + threadIdx.x) >> 6;
  int lane = threadIdx.x & 63;
  if (wid >= nseg) return;
  int b0 = basea[wid], cnt = cnta[wid];
  float s = 0.f;
  for (int i = 0; i < cnt; i++) {
    int e = bucket[b0 + i];
    s += (float)src[(long)e * 64 + lane];
  }
  dst[(long)wid * 64 + lane] = s / (float)(cnt > 0 ? cnt : 1);
}

// ---------------- head gemm: g2 = relu(g1 @ W + b) ----------------

__global__ __launch_bounds__(256) void k_head(const float* g1, const float* W,
                                              const float* bias, float* g2) {
  __shared__ float Wl[4096];
  __shared__ float inl[32 * 64];
  __shared__ float bl[64];
  int t = threadIdx.x;
  int brow = blockIdx.x * 32;
#pragma unroll
  for (int i = 0; i < 4; i++) ((float4*)Wl)[t + 256 * i] = ((const float4*)W)[t + 256 * i];
  if (t < 64) bl[t] = bias[t];
  __syncthreads();
#pragma unroll
  for (int i = 0; i < 2; i++) {
    int idx = t + 256 * i;
    int r = idx >> 4, q = idx & 15;
    ((float4*)inl)[idx] = ((const float4*)(g1 + (long)(brow + r) * 64))[q];
  }
  __syncthreads();
  int c = t & 63, rq = t >> 6;
  float acc[8];
#pragma unroll
  for (int i = 0; i < 8; i++) acc[i] = 0.f;
  for (int j = 0; j < 64; j += 4) {
    float w0 = Wl[(j + 0) * 64 + c], w1 = Wl[(j + 1) * 64 + c];
    float w2 = Wl[(j + 2) * 64 + c], w3 = Wl[(j + 3) * 64 + c];
#pragma unroll
    for (int i = 0; i < 8; i++) {
      int r = rq * 8 + i;
      float4 v = *(const float4*)&inl[r * 64 + j];
      acc[i] += v.x * w0 + v.y * w1 + v.z * w2 + v.w * w3;
    }
  }
#pragma unroll
  for (int i = 0; i < 8; i++) {
    long r = brow + rq * 8 + i;
    float v = acc[i] + bl[c];
    g2[r * 64 + c] = v > 0.f ? v : 0.f;
  }
}

__global__ __launch_bounds__(256) void k_final(const float* g2, const float* linW,
                                               const float* linb, float* out) {
  int wid = (blockIdx.x * 256 + threadIdx.x) >> 6;
  int lane = threadIdx.x & 63;
  if (wid >= NBATCH) return;
  float v = g2[(long)wid * 64 + lane] * linW[lane];
  for (int o = 32; o > 0; o >>= 1) v += __shfl_down(v, o, 64);
  if (lane == 0) out[wid] = v + linb[0];
}

__global__ __launch_bounds__(256) void k_zero_out(float* out, int n) {
  for (int i = blockIdx.x * 256 + threadIdx.x; i < n; i += gridDim.x * 256) out[i] = 0.f;
}

// ---------------- launcher ----------------

extern "C" void kernel_launch(void* const* d_in, const int* in_sizes, int n_in,
                              void* d_out, int out_size, void* d_ws, size_t ws_size,
                              hipStream_t stream) {
  (void)in_sizes; (void)n_in;

  const int* x_atom = (const int*)d_in[0];
  const int* vals[5] = {(const int*)d_in[1], (const int*)d_in[4], (const int*)d_in[7],
                        (const int*)d_in[10], (const int*)d_in[13]};
  const int* rowm[5] = {(const int*)d_in[2], (const int*)d_in[5], (const int*)d_in[8],
                        (const int*)d_in[11], (const int*)d_in[14]};
  const int* batch = (const int*)d_in[16];
  const float* aemb0 = (const float*)d_in[17];
  const float* aemb1 = (const float*)d_in[18];
  const float* aemb2 = (const float*)d_in[19];
  const float* path_emb = (const float*)d_in[20];
  const float* cycle_emb = (const float*)d_in[21];
  const float* pW_a2p = (const float*)d_in[22];
  const float* pb_a2p = (const float*)d_in[23];
  const float* pW_p2a = (const float*)d_in[24];
  const float* pb_p2a = (const float*)d_in[25];
  const float* pK = (const float*)d_in[26];
  const float* pKb = (const float*)d_in[27];
  const float* cW_a2p = (const float*)d_in[28];
  const float* cb_a2p = (const float*)d_in[29];
  const float* cW_p2a = (const float*)d_in[30];
  const float* cb_p2a = (const float*)d_in[31];
  const float* cK = (const float*)d_in[32];
  const float* cKb = (const float*)d_in[33];
  const float* alW = (const float*)d_in[34];
  const float* alb = (const float*)d_in[35];
  const float* linW = (const float*)d_in[36];
  const float* linb = (const float*)d_in[37];

  static const int Em[5] = {300000, 400000, 500000, 200000, 240000};
  static const int Km[5] = {3, 4, 5, 5, 6};
  static const int Ppb[5] = {32, 24, 16, 16, 16};
  const int CNT_N = 5 * 100000 + NBATCH;  // 504096
  const int ACC_ROWS = 100032;            // padded to apply grid (1563*64)

  char* ws = (char*)d_ws;
  size_t off = 0;
  auto alloc = [&](size_t nbytes) -> char* {
    char* p = ws + off;
    off = (off + nbytes + 255) & ~(size_t)255;
    return p;
  };
  f16* x = (f16*)alloc((size_t)NA * 64 * 2);   // f16 master
  f16* xh = (f16*)alloc((size_t)NA * 64 * 2);  // f16 snapshot for group-local gathers
  __half* xp[5];
  for (int m = 0; m < 5; m++) xp[m] = (__half*)alloc((size_t)Em[m] * 64 * 2);
  f16* acc = (f16*)alloc((size_t)ACC_ROWS * 64 * 2);  // f16 accumulator
  float* g1 = (float*)alloc((size_t)NBATCH * 64 * 4);
  float* g2 = (float*)alloc((size_t)NBATCH * 64 * 4);
  int* cnt = (int*)alloc((size_t)CNT_N * 4);
  int* basea_b = (int*)alloc((size_t)(NBATCH + 1) * 4);
  int* cursor_b = (int*)alloc((size_t)NBATCH * 4);
  int* bucket = (int*)alloc((size_t)NA * 4);
  f16* Bp = (f16*)alloc((size_t)10 * 12288 * 2);  // prepacked conv kernels
  f16* Wpk = (f16*)alloc((size_t)20 * 4096 * 2);  // prepacked p2a+a2p weights

  if (ws_size < off) {  // workspace too small: emit readable failure, not a fault
    k_zero_out<<<16, 256, 0, stream>>>((float*)d_out, out_size);
    return;
  }

  // ---- counts (all maps + batch) and batch CSR
  MapsParams mp;
  {
    int s = 0;
    for (int m = 0; m < 5; m++) {
      mp.row[m] = rowm[m]; mp.cnt_off[m] = m * 100000;
      mp.start[m] = s; s += Em[m];
    }
    mp.row[5] = batch; mp.cnt_off[5] = 500000; mp.start[5] = s;
    mp.total = s + NA;
  }
  (void)hipMemsetAsync(cnt, 0, (size_t)CNT_N * 4, stream);
  (void)hipMemsetAsync(acc, 0, (size_t)ACC_ROWS * 64 * 2, stream);
  k_count<<<2048, 256, 0, stream>>>(mp, cnt);
  k_scan_batch<<<1, 256, 0, stream>>>(cnt + 500000, basea_b);
  (void)hipMemcpyAsync(cursor_b, basea_b, (size_t)NBATCH * 4, hipMemcpyDeviceToDevice, stream);
  k_fill_batch<<<128, 256, 0, stream>>>(batch, cursor_b, bucket);

  // ---- prepack weights + feature init
  k_prepB<<<480, 256, 0, stream>>>(pK, cK, Bp);
  k_prepW<<<320, 256, 0, stream>>>(pW_p2a, cW_p2a, pW_a2p, cW_a2p, Wpk);
  k_atom_init<<<NA * 16 / 256, 256, 0, stream>>>(x_atom, aemb0, aemb1, aemb2, x);
  {
    PInit pp;
    int s8 = 0;
    for (int m = 0; m < 5; m++) {
      pp.dst[m] = xp[m];
      pp.vals[m] = vals[m];
      pp.tab[m] = (m < 3) ? (path_emb + m * 6 * 64) : (cycle_emb + (m - 3) * 4 * 64);
      pp.start8[m] = s8;
      s8 += Em[m] * 8;
    }
    pp.total8 = s8;
    k_path_init<<<8192, 256, 0, stream>>>(pp);
  }

  int apply_blocks = ACC_ROWS / 64;  // 1563
  size_t snap_bytes = (size_t)NA * 64 * 2;

  // ---- layers
  for (int l = 0; l < 2; l++) {
    // === paths group (maps 0..2), non-cyclic
    (void)hipMemcpyAsync(xh, x, snap_bytes, hipMemcpyDeviceToDevice, stream);
    {
      FusedParams fp{};
      fp.nseg = 3; fp.cyclic = 0; fp.xh = xh;
      int bs = 0;
      for (int m = 0; m < 3; m++) {
        fp.gidx[m] = rowm[m]; fp.xp[m] = xp[m];
        fp.Wa[m] = Wpk + (size_t)(10 + l * 3 + m) * 4096;
        fp.ba[m] = pb_a2p + (l * 3 + m) * 64;
        fp.Bp[m] = Bp + (size_t)(l * 3 + m) * 12288;
        fp.Kb[m] = pKb + (l * 3 + m) * 64;
        fp.k[m] = Km[m]; fp.P[m] = Em[m] / Km[m]; fp.ppb[m] = Ppb[m];
        fp.blk_start[m] = bs;
        bs += (fp.P[m] + fp.ppb[m] - 1) / fp.ppb[m];
      }
      k_fused<<<bs, 256, 0, stream>>>(fp);

      for (int m = 0; m < 3; m++) {
        k_scatter<<<1024, 256, 0, stream>>>((const f16*)xp[m], rowm[m], (__half2*)acc, Em[m]);
        k_apply<<<apply_blocks, 256, 0, stream>>>(acc, cnt + m * 100000,
                                                  Wpk + (size_t)(l * 3 + m) * 4096,
                                                  pb_p2a + (l * 3 + m) * 64, x);
      }
    }
    // === cycles group (maps 3..4), cyclic
    (void)hipMemcpyAsync(xh, x, snap_bytes, hipMemcpyDeviceToDevice, stream);
    {
      FusedParams fp{};
      fp.nseg = 2; fp.cyclic = 1; fp.xh = xh;
      int bs = 0;
      for (int m = 3; m < 5; m++) {
        int i = m - 3;
        fp.gidx[i] = rowm[m]; fp.xp[i] = xp[m];
        fp.Wa[i] = Wpk + (size_t)(16 + l * 2 + i) * 4096;
        fp.ba[i] = cb_a2p + (l * 2 + i) * 64;
        fp.Bp[i] = Bp + (size_t)(6 + l * 2 + i) * 12288;
        fp.Kb[i] = cKb + (l * 2 + i) * 64;
        fp.k[i] = Km[m]; fp.P[i] = Em[m] / Km[m]; fp.ppb[i] = Ppb[m];
        fp.blk_start[i] = bs;
        bs += (fp.P[i] + fp.ppb[i] - 1) / fp.ppb[i];
      }
      k_fused<<<bs, 256, 0, stream>>>(fp);

      for (int m = 3; m < 5; m++) {
        int i = m - 3;
        k_scatter<<<1024, 256, 0, stream>>>((const f16*)xp[m], rowm[m], (__half2*)acc, Em[m]);
        k_apply<<<apply_blocks, 256, 0, stream>>>(acc, cnt + m * 100000,
                                                  Wpk + (size_t)(6 + l * 2 + i) * 4096,
                                                  cb_p2a + (l * 2 + i) * 64, x);
      }
    }
  }

  // ---- head
  k_meanscatter<<<NBATCH / 4, 256, 0, stream>>>(x, bucket, basea_b, cnt + 500000,
                                                g1, NBATCH);
  k_head<<<NBATCH / 32, 256, 0, stream>>>(g1, alW, alb, g2);
  k_final<<<NBATCH / 4, 256, 0, stream>>>(g2, linW, linb, (float*)d_out);
}

// Round 16
// 1110.523 us; speedup vs baseline: 1.8915x; 1.0960x over previous
//
#include <hip/hip_runtime.h>
#include <hip/hip_fp16.h>

#define NA 100000
#define NBATCH 4096
#define MLD 68
#define CLD2 66

typedef _Float16 f16;
typedef f16 half8 __attribute__((ext_vector_type(8)));
typedef f16 half4 __attribute__((ext_vector_type(4)));
typedef f16 hv2 __attribute__((ext_vector_type(2)));
typedef float f32x4 __attribute__((ext_vector_type(4)));
union H8 { uint4 u; __half h[8]; };
union HU { uint4 u; half8 h; f16 s[8]; };

// packed f16 atomic add (HW pk_add_f16 path)
__device__ inline void pk_atomic_add(__half2* addr, hv2 v) {
#if __has_builtin(__builtin_amdgcn_flat_atomic_fadd_v2f16)
  __builtin_amdgcn_flat_atomic_fadd_v2f16((hv2*)addr, v);
#else
  unsafeAtomicAdd(addr, *(__half2*)&v);
#endif
}

// ---------------- CSR build (5 maps + batch) ----------------

struct MapsParams {
  const int* row[6];
  int cnt_off[6];
  int start[6];
  int total;
};

__global__ __launch_bounds__(256) void k_count(MapsParams mp, int* cnt) {
  for (int g = blockIdx.x * 256 + threadIdx.x; g < mp.total; g += gridDim.x * 256) {
    int m = 0;
#pragma unroll
    for (int i = 1; i < 6; i++) if (g >= mp.start[i]) m = i;
    int e = g - mp.start[m];
    atomicAdd(&cnt[mp.cnt_off[m] + mp.row[m][e]], 1);
  }
}

__global__ __launch_bounds__(256) void k_scanA(const int* in, int* out, int* bsums, int n) {
  __shared__ int s[256];
  int t = threadIdx.x;
  int base = blockIdx.x * 2048 + t * 8;
  int v[8]; int sum = 0;
#pragma unroll
  for (int i = 0; i < 8; i++) { v[i] = (base + i < n) ? in[base + i] : 0; sum += v[i]; }
  s[t] = sum;
  __syncthreads();
  for (int d = 1; d < 256; d <<= 1) {
    int x = (t >= d) ? s[t - d] : 0;
    __syncthreads();
    s[t] += x;
    __syncthreads();
  }
  if (t == 255) bsums[blockIdx.x] = s[255];
  int run = s[t] - sum;
#pragma unroll
  for (int i = 0; i < 8; i++) { if (base + i < n) out[base + i] = run; run += v[i]; }
}

__global__ __launch_bounds__(256) void k_scanB(int* a, int n) {
  __shared__ int s[256];
  int t = threadIdx.x;
  int carry = 0;
  for (int c0 = 0; c0 < n; c0 += 256) {
    int v = (c0 + t < n) ? a[c0 + t] : 0;
    s[t] = v;
    __syncthreads();
    for (int d = 1; d < 256; d <<= 1) {
      int x = (t >= d) ? s[t - d] : 0;
      __syncthreads();
      s[t] += x;
      __syncthreads();
    }
    if (c0 + t < n) a[c0 + t] = s[t] - v + carry;
    int tot = s[255];
    __syncthreads();
    carry += tot;
  }
}

__global__ __launch_bounds__(256) void k_scanC(int* out, const int* bsums, int n) {
  int addv = bsums[blockIdx.x];
  int base = blockIdx.x * 2048 + threadIdx.x * 8;
#pragma unroll
  for (int i = 0; i < 8; i++) if (base + i < n) out[base + i] += addv;
}

__global__ __launch_bounds__(256) void k_fill(MapsParams mp, int* cursor, int2* bucket) {
  for (int g = blockIdx.x * 256 + threadIdx.x; g < mp.total; g += gridDim.x * 256) {
    int m = 0;
#pragma unroll
    for (int i = 1; i < 6; i++) if (g >= mp.start[i]) m = i;
    int e = g - mp.start[m];
    int a = mp.row[m][e];
    int pos = atomicAdd(&cursor[mp.cnt_off[m] + a], 1);
    int2 v; v.x = e; v.y = a;
    bucket[pos] = v;
  }
}

// ---------------- feature init (x stored f16) ----------------

__global__ __launch_bounds__(256) void k_atom_init(const int* xa, const float* e0,
                                                   const float* e1, const float* e2, f16* x) {
  int idx = blockIdx.x * 256 + threadIdx.x;
  if (idx >= NA * 16) return;
  int a = idx >> 4, q = idx & 15;
  int f0 = xa[a * 3], f1 = xa[a * 3 + 1], f2 = xa[a * 3 + 2];
  float4 v0 = ((const float4*)e0)[f0 * 16 + q];
  float4 v1 = ((const float4*)e1)[f1 * 16 + q];
  float4 v2 = ((const float4*)e2)[f2 * 16 + q];
  half4 h = {(f16)(v0.x + v1.x + v2.x), (f16)(v0.y + v1.y + v2.y),
             (f16)(v0.z + v1.z + v2.z), (f16)(v0.w + v1.w + v2.w)};
  ((half4*)x)[idx] = h;
}

struct PInit {
  __half* dst[5];
  const int* vals[5];
  const float* tab[5];
  int start8[5];
  int total8;
};

__global__ __launch_bounds__(256) void k_path_init(PInit pp) {
  for (int g = blockIdx.x * 256 + threadIdx.x; g < pp.total8; g += gridDim.x * 256) {
    int m = 0;
#pragma unroll
    for (int i = 1; i < 5; i++) if (g >= pp.start8[i]) m = i;
    int lc = g - pp.start8[m];
    int e = lc >> 3, q = lc & 7;
    int v = pp.vals[m][e];
    const float* src = pp.tab[m] + v * 64 + q * 8;
    H8 o;
#pragma unroll
    for (int j = 0; j < 8; j++) o.h[j] = __float2half(src[j]);
    ((uint4*)pp.dst[m])[lc] = o.u;
  }
}

// ---------------- prepack conv kernels to fp16 MFMA-B layout ----------------

__global__ __launch_bounds__(256) void k_prepB(const float* pK, const float* cK, f16* Bp) {
  int tid = blockIdx.x * 256 + threadIdx.x;
  if (tid >= 10 * 12288) return;
  int set = tid / 12288, pos = tid % 12288;
  int j = pos & 7, lane = (pos >> 3) & 63, kcnt = pos >> 9;
  int kc = kcnt % 6, nt = kcnt / 6;
  int k = kc * 32 + ((lane >> 4) << 3) + j;
  int n = (nt << 4) + (lane & 15);
  int w = k >> 6, ji = k & 63;
  const float* K = (set < 6) ? (pK + set * 3 * 4096) : (cK + (set - 6) * 3 * 4096);
  float v = K[w * 4096 + ji * 64 + n];
  if (set >= 6) v = 0.5f * (v + K[(2 - w) * 4096 + ji * 64 + n]);
  Bp[tid] = (f16)v;
}

// ---------------- prepack 64x64 weights to fp16 MFMA-B layout ----------------

__global__ __launch_bounds__(256) void k_prepW(const float* pW, const float* cW,
                                               const float* pWa, const float* cWa, f16* Wp) {
  int tid = blockIdx.x * 256 + threadIdx.x;
  if (tid >= 20 * 4096) return;
  int set = tid >> 12, pos = tid & 4095;
  int j = pos & 7, lane = (pos >> 3) & 63, ntkc = pos >> 9;
  int kc = ntkc & 1, nt = ntkc >> 1;
  int k = kc * 32 + ((lane >> 4) << 3) + j;
  int n = (nt << 4) + (lane & 15);
  const float* W;
  if (set < 6) W = pW + set * 4096;
  else if (set < 10) W = cW + (set - 6) * 4096;
  else if (set < 16) W = pWa + (set - 10) * 4096;
  else W = cWa + (set - 16) * 4096;
  Wp[tid] = (f16)W[k * 64 + n];
}

// ---------------- fused a2p+conv per map-group (batched segs) ----------------
//   t = xp_old + relu(gather(x) @ Wa + ba)
//   xp_new = t + relu(conv3(t) @ K + Kb)
// Safe to gather from live x: all fused blocks of a group complete before any apply.

struct FusedParams {
  const f16* xh;
  const int* gidx[3];
  __half* xp[3];
  const f16* Wa[3];
  const float* ba[3];
  const f16* Bp[3];
  const float* Kb[3];
  int k[3];
  int P[3];
  int ppb[3];
  int blk_start[3];
  int nseg;
  int cyclic;
};

__global__ __launch_bounds__(256) void k_fused(FusedParams p) {
  __shared__ uint4 CfU[1584];
  __shared__ uint4 xn4[873];
  __shared__ float bl[64], kbl[64];
  __shared__ int ridx[96];
  float* Cf = (float*)CfU;
  uint4* Af = CfU;
  int bid = blockIdx.x;
  int seg = 0;
#pragma unroll
  for (int i = 1; i < 3; i++) if (i < p.nseg && bid >= p.blk_start[i]) seg = i;
  int kk = p.k[seg], ppb = p.ppb[seg], P = p.P[seg];
  int cyc = p.cyclic;
  int t = threadIdx.x;
  int p0 = (bid - p.blk_start[seg]) * ppb;
  int np = min(ppb, P - p0);
  int R = np * kk;
  int mtb = R >> 4;
  long ebase = (long)p0 * kk;
  if (t < 64) { bl[t] = p.ba[seg][t]; kbl[t] = p.Kb[seg][t]; }
  if (t < 9) { uint4 z; z.x = z.y = z.z = z.w = 0; xn4[96 * 9 + t] = z; }
  if (t < R) ridx[t] = p.gidx[seg][ebase + t];
  __syncthreads();
  const uint4* xh4 = (const uint4*)p.xh;
  int nunits = mtb * 128;
  for (int j = t; j < nunits; j += 256) {
    int frag = j >> 6, lb = j & 63;
    int row = ((frag >> 1) << 4) + (lb & 15);
    int ch = ((frag & 1) << 2) + (lb >> 4);
    Af[j] = xh4[(long)ridx[row] * 8 + ch];
  }
  __syncthreads();
  int lane = t & 63, wid = t >> 6;
  int wave_n = wid & 1, wave_m = wid >> 1;
  int mtA = (mtb + 1) >> 1;
  int m0 = wave_m ? mtA : 0;
  int mcnt = wave_m ? (mtb - mtA) : mtA;
  f32x4 acc1[3][2];
#pragma unroll
  for (int i = 0; i < 3; i++)
#pragma unroll
    for (int jn = 0; jn < 2; jn++) { f32x4 z = {0.f, 0.f, 0.f, 0.f}; acc1[i][jn] = z; }
  const uint4* Wau = (const uint4*)p.Wa[seg];
#pragma unroll
  for (int kc = 0; kc < 2; kc++) {
    HU a[3], b[2];
#pragma unroll
    for (int jn = 0; jn < 2; jn++)
      b[jn].u = Wau[(((wave_n * 2 + jn) << 1) + kc) * 64 + lane];
#pragma unroll
    for (int i = 0; i < 3; i++)
      if (i < mcnt) a[i].u = Af[(((m0 + i) << 1) + kc) * 64 + lane];
#pragma unroll
    for (int i = 0; i < 3; i++)
      if (i < mcnt) {
#pragma unroll
        for (int jn = 0; jn < 2; jn++)
          acc1[i][jn] = __builtin_amdgcn_mfma_f32_16x16x32_f16(a[i].h, b[jn].h, acc1[i][jn], 0, 0, 0);
      }
  }
  __syncthreads();
#pragma unroll
  for (int i = 0; i < 3; i++) {
    if (i >= mcnt) continue;
#pragma unroll
    for (int jn = 0; jn < 2; jn++) {
      int n = ((wave_n * 2 + jn) << 4) + (lane & 15);
      float bv = bl[n];
      int rb = ((m0 + i) << 4) + ((lane >> 4) << 2);
#pragma unroll
      for (int reg = 0; reg < 4; reg++) {
        float v = acc1[i][jn][reg] + bv;
        Cf[(rb + reg) * CLD2 + n] = v > 0.f ? v : 0.f;
      }
    }
  }
  __syncthreads();
  uint4* xg = (uint4*)(p.xp[seg] + (long)ebase * 64);
  for (int idx = t; idx < R * 8; idx += 256) {
    int row = idx >> 3, ch = idx & 7;
    HU res; res.u = xg[idx];
    const float* c = &Cf[row * CLD2 + ch * 8];
    HU o;
#pragma unroll
    for (int j = 0; j < 8; j++) o.s[j] = (f16)((float)res.s[j] + c[j]);
    xn4[row * 9 + ch] = o.u;
  }
  __syncthreads();
  f32x4 acc2[3][2];
#pragma unroll
  for (int i = 0; i < 3; i++)
#pragma unroll
    for (int jn = 0; jn < 2; jn++) { f32x4 z = {0.f, 0.f, 0.f, 0.f}; acc2[i][jn] = z; }
  int rdw[3][3];
#pragma unroll
  for (int i = 0; i < 3; i++) {
    if (i >= mcnt) continue;
    int mr = ((m0 + i) << 4) + (lane & 15);
    int sm = mr % kk;
    rdw[i][1] = mr;
    rdw[i][0] = (sm >= 1) ? mr - 1 : (cyc ? mr + kk - 1 : 96);
    rdw[i][2] = (sm + 1 < kk) ? mr + 1 : (cyc ? mr + 1 - kk : 96);
  }
  const uint4* Bg = (const uint4*)p.Bp[seg];
  for (int kc = 0; kc < 6; kc++) {
    int w = kc >> 1;
    int chunk = ((kc & 1) << 2) + (lane >> 4);
    HU a[3], b[2];
#pragma unroll
    for (int jn = 0; jn < 2; jn++)
      b[jn].u = Bg[((wave_n * 2 + jn) * 6 + kc) * 64 + lane];
#pragma unroll
    for (int i = 0; i < 3; i++)
      if (i < mcnt) a[i].u = xn4[rdw[i][w] * 9 + chunk];
#pragma unroll
    for (int i = 0; i < 3; i++)
      if (i < mcnt) {
#pragma unroll
        for (int jn = 0; jn < 2; jn++)
          acc2[i][jn] = __builtin_amdgcn_mfma_f32_16x16x32_f16(a[i].h, b[jn].h, acc2[i][jn], 0, 0, 0);
      }
  }
  __syncthreads();
#pragma unroll
  for (int i = 0; i < 3; i++) {
    if (i >= mcnt) continue;
#pragma unroll
    for (int jn = 0; jn < 2; jn++) {
      int n = ((wave_n * 2 + jn) << 4) + (lane & 15);
      float bv = kbl[n];
      int rb = ((m0 + i) << 4) + ((lane >> 4) << 2);
#pragma unroll
      for (int reg = 0; reg < 4; reg++) {
        float v = acc2[i][jn][reg] + bv;
        Cf[(rb + reg) * CLD2 + n] = v > 0.f ? v : 0.f;
      }
    }
  }
  __syncthreads();
  for (int idx = t; idx < R * 8; idx += 256) {
    int row = idx >> 3, ch = idx & 7;
    HU res; res.u = xn4[row * 9 + ch];
    const float* c = &Cf[row * CLD2 + ch * 8];
    HU o;
#pragma unroll
    for (int j = 0; j < 8; j++) o.s[j] = (f16)((float)res.s[j] + c[j]);
    xg[idx] = o.u;
  }
}

// ---------------- p2a scatter v3: CSR-ordered aggregation + pk f16 atomics -------------
// half-wave (32 lanes) takes 8 consecutive bucket entries (same-atom adjacency by CSR);
// pre-sums same-atom rows with pk_add in registers; one atomic per distinct atom.

__global__ __launch_bounds__(256) void k_scatter(const f16* xp, const int2* bucket,
                                                 __half2* acc, int E) {
  int ghw = (blockIdx.x * 256 + threadIdx.x) >> 5;
  int l = threadIdx.x & 31;
  int nhw = (gridDim.x * 256) >> 5;
  const hv2* xp2 = (const hv2*)xp;
  for (int j0 = ghw * 8; j0 < E; j0 += nhw * 8) {
    if (j0 + 8 <= E) {
      int2 e[8];
#pragma unroll
      for (int u = 0; u < 8; u++) e[u] = bucket[j0 + u];
      hv2 v[8];
#pragma unroll
      for (int u = 0; u < 8; u++) v[u] = xp2[(long)e[u].x * 32 + l];
      hv2 vacc = v[0];
      int cur = e[0].y;
#pragma unroll
      for (int u = 1; u < 8; u++) {
        if (e[u].y == cur) {
          vacc = vacc + v[u];
        } else {
          pk_atomic_add(&acc[(long)cur * 32 + l], vacc);
          cur = e[u].y;
          vacc = v[u];
        }
      }
      pk_atomic_add(&acc[(long)cur * 32 + l], vacc);
    } else {
      int nc = E - j0;
      int2 e0 = bucket[j0];
      hv2 vacc = xp2[(long)e0.x * 32 + l];
      int cur = e0.y;
      for (int u = 1; u < nc; u++) {
        int2 eu = bucket[j0 + u];
        hv2 v = xp2[(long)eu.x * 32 + l];
        if (eu.y == cur) {
          vacc = vacc + v;
        } else {
          pk_atomic_add(&acc[(long)cur * 32 + l], vacc);
          cur = eu.y;
          vacc = v;
        }
      }
      pk_atomic_add(&acc[(long)cur * 32 + l], vacc);
    }
  }
}

// ---------------- p2a apply: x += relu(acc/cnt @ W + b); x f16; self-zeroes acc ---------

__global__ __launch_bounds__(256) void k_apply(f16* acc, const int* cnt, const f16* Wp,
                                               const float* bias, f16* x) {
  __shared__ float mean[64 * MLD];
  __shared__ uint4 Af[512];
  __shared__ float invl[64];
  __shared__ float bl[64];
  int t = threadIdx.x;
  int a0 = blockIdx.x * 64;
  if (t < 64) {
    int cb = cnt[a0 + t];
    invl[t] = 1.f / (float)(cb > 0 ? cb : 1);
    bl[t] = bias[t];
  }
  uint4* acc4 = (uint4*)acc;
#pragma unroll
  for (int i = 0; i < 2; i++) {
    int idx = t + 256 * i;
    int r = idx >> 3, q = idx & 7;
    HU v; v.u = acc4[(long)a0 * 8 + idx];
    uint4 z4; z4.x = z4.y = z4.z = z4.w = 0;
    acc4[(long)a0 * 8 + idx] = z4;
    float* mr = &mean[r * MLD + q * 8];
#pragma unroll
    for (int j = 0; j < 8; j++) mr[j] = (float)v.s[j];
  }
  __syncthreads();
#pragma unroll
  for (int i = 0; i < 2; i++) {
    int j = t + 256 * i;
    int frag = j >> 6, lb = j & 63;
    int row = ((frag >> 1) << 4) + (lb & 15);
    int ch = ((frag & 1) << 2) + (lb >> 4);
    float inv = invl[row];
    const float* mr = &mean[row * MLD + ch * 8];
    HU o;
#pragma unroll
    for (int jj = 0; jj < 8; jj++) o.h[jj] = (f16)(mr[jj] * inv);
    Af[j] = o.u;
  }
  __syncthreads();
  int lane = t & 63, wid = t >> 6;
  HU af0, af1;
  af0.u = Af[((wid << 1) + 0) * 64 + lane];
  af1.u = Af[((wid << 1) + 1) * 64 + lane];
  const uint4* Wu = (const uint4*)Wp;
  int rowb = a0 + wid * 16 + ((lane >> 4) << 2);
#pragma unroll
  for (int nt = 0; nt < 4; nt++) {
    HU b0, b1;
    b0.u = Wu[((nt << 1) + 0) * 64 + lane];
    b1.u = Wu[((nt << 1) + 1) * 64 + lane];
    f32x4 z = {0.f, 0.f, 0.f, 0.f};
    z = __builtin_amdgcn_mfma_f32_16x16x32_f16(af0.h, b0.h, z, 0, 0, 0);
    z = __builtin_amdgcn_mfma_f32_16x16x32_f16(af1.h, b1.h, z, 0, 0, 0);
    int n = nt * 16 + (lane & 15);
    float bv = bl[n];
#pragma unroll
    for (int r = 0; r < 4; r++) {
      int atom = rowb + r;
      if (atom < NA) {
        float vv = z[r] + bv;
        vv = vv > 0.f ? vv : 0.f;
        long oi = (long)atom * 64 + n;
        x[oi] = (f16)((float)x[oi] + vv);
      }
    }
  }
}

// ---------------- batch mean over f16 x ----------------

__global__ __launch_bounds__(256) void k_meanscatter(const f16* src, const int2* bucket,
                                                     const int* basea, const int* cnta,
                                                     float* dst, int nseg) {
  int wid = (blockIdx.x * 256 + threadIdx.x) >> 6;
  int lane = threadIdx.x & 63;
  if (wid >= nseg) return;
  int b0 = basea[wid], cnt = cnta[wid];
  float s = 0.f;
  for (int i = 0; i < cnt; i++) {
    int e = bucket[b0 + i].x;
    s += (float)src[(long)e * 64 + lane];
  }
  dst[(long)wid * 64 + lane] = s / (float)(cnt > 0 ? cnt : 1);
}

// ---------------- head gemm ----------------

__global__ __launch_bounds__(256) void k_head(const float* g1, const float* W,
                                              const float* bias, float* g2) {
  __shared__ float Wl[4096];
  __shared__ float inl[32 * 64];
  __shared__ float bl[64];
  int t = threadIdx.x;
  int brow = blockIdx.x * 32;
#pragma unroll
  for (int i = 0; i < 4; i++) ((float4*)Wl)[t + 256 * i] = ((const float4*)W)[t + 256 * i];
  if (t < 64) bl[t] = bias[t];
  __syncthreads();
#pragma unroll
  for (int i = 0; i < 2; i++) {
    int idx = t + 256 * i;
    int r = idx >> 4, q = idx & 15;
    ((float4*)inl)[idx] = ((const float4*)(g1 + (long)(brow + r) * 64))[q];
  }
  __syncthreads();
  int c = t & 63, rq = t >> 6;
  float acc[8];
#pragma unroll
  for (int i = 0; i < 8; i++) acc[i] = 0.f;
  for (int j = 0; j < 64; j += 4) {
    float w0 = Wl[(j + 0) * 64 + c], w1 = Wl[(j + 1) * 64 + c];
    float w2 = Wl[(j + 2) * 64 + c], w3 = Wl[(j + 3) * 64 + c];
#pragma unroll
    for (int i = 0; i < 8; i++) {
      int r = rq * 8 + i;
      float4 v = *(const float4*)&inl[r * 64 + j];
      acc[i] += v.x * w0 + v.y * w1 + v.z * w2 + v.w * w3;
    }
  }
#pragma unroll
  for (int i = 0; i < 8; i++) {
    long r = brow + rq * 8 + i;
    float v = acc[i] + bl[c];
    g2[r * 64 + c] = v > 0.f ? v : 0.f;
  }
}

__global__ __launch_bounds__(256) void k_final(const float* g2, const float* linW,
                                               const float* linb, float* out) {
  int wid = (blockIdx.x * 256 + threadIdx.x) >> 6;
  int lane = threadIdx.x & 63;
  if (wid >= NBATCH) return;
  float v = g2[(long)wid * 64 + lane] * linW[lane];
  for (int o = 32; o > 0; o >>= 1) v += __shfl_down(v, o, 64);
  if (lane == 0) out[wid] = v + linb[0];
}

__global__ __launch_bounds__(256) void k_zero_out(float* out, int n) {
  for (int i = blockIdx.x * 256 + threadIdx.x; i < n; i += gridDim.x * 256) out[i] = 0.f;
}

// ---------------- launcher ----------------

extern "C" void kernel_launch(void* const* d_in, const int* in_sizes, int n_in,
                              void* d_out, int out_size, void* d_ws, size_t ws_size,
                              hipStream_t stream) {
  (void)in_sizes; (void)n_in;

  const int* x_atom = (const int*)d_in[0];
  const int* vals[5] = {(const int*)d_in[1], (const int*)d_in[4], (const int*)d_in[7],
                        (const int*)d_in[10], (const int*)d_in[13]};
  const int* rowm[5] = {(const int*)d_in[2], (const int*)d_in[5], (const int*)d_in[8],
                        (const int*)d_in[11], (const int*)d_in[14]};
  const int* batch = (const int*)d_in[16];
  const float* aemb0 = (const float*)d_in[17];
  const float* aemb1 = (const float*)d_in[18];
  const float* aemb2 = (const float*)d_in[19];
  const float* path_emb = (const float*)d_in[20];
  const float* cycle_emb = (const float*)d_in[21];
  const float* pW_a2p = (const float*)d_in[22];
  const float* pb_a2p = (const float*)d_in[23];
  const float* pW_p2a = (const float*)d_in[24];
  const float* pb_p2a = (const float*)d_in[25];
  const float* pK = (const float*)d_in[26];
  const float* pKb = (const float*)d_in[27];
  const float* cW_a2p = (const float*)d_in[28];
  const float* cb_a2p = (const float*)d_in[29];
  const float* cW_p2a = (const float*)d_in[30];
  const float* cb_p2a = (const float*)d_in[31];
  const float* cK = (const float*)d_in[32];
  const float* cKb = (const float*)d_in[33];
  const float* alW = (const float*)d_in[34];
  const float* alb = (const float*)d_in[35];
  const float* linW = (const float*)d_in[36];
  const float* linb = (const float*)d_in[37];

  static const int Em[5] = {300000, 400000, 500000, 200000, 240000};
  static const int Km[5] = {3, 4, 5, 5, 6};
  static const int Ppb[5] = {32, 24, 16, 16, 16};
  static const int MapStart[5] = {0, 300000, 700000, 1200000, 1400000};
  const int CNT_N = 5 * 100000 + NBATCH;  // 504096
  const int BUCKET_N = 1640000 + NA;      // 1740000
  const int ACC_ROWS = 100032;

  char* ws = (char*)d_ws;
  size_t off = 0;
  auto alloc = [&](size_t nbytes) -> char* {
    char* p = ws + off;
    off = (off + nbytes + 255) & ~(size_t)255;
    return p;
  };
  f16* x = (f16*)alloc((size_t)NA * 64 * 2);   // f16 master
  __half* xp[5];
  for (int m = 0; m < 5; m++) xp[m] = (__half*)alloc((size_t)Em[m] * 64 * 2);
  f16* acc = (f16*)alloc((size_t)ACC_ROWS * 64 * 2);
  float* g1 = (float*)alloc((size_t)NBATCH * 64 * 4);
  float* g2 = (float*)alloc((size_t)NBATCH * 64 * 4);
  int* cnt = (int*)alloc((size_t)CNT_N * 4);
  int* basea = (int*)alloc((size_t)CNT_N * 4);
  int* cursor = (int*)alloc((size_t)CNT_N * 4);
  int2* bucket = (int2*)alloc((size_t)BUCKET_N * 8);
  int* bsums = (int*)alloc(256 * 4);
  f16* Bp = (f16*)alloc((size_t)10 * 12288 * 2);
  f16* Wpk = (f16*)alloc((size_t)20 * 4096 * 2);

  if (ws_size < off) {
    k_zero_out<<<16, 256, 0, stream>>>((float*)d_out, out_size);
    return;
  }

  // ---- CSR build (all maps + batch)
  MapsParams mp;
  {
    int s = 0;
    for (int m = 0; m < 5; m++) {
      mp.row[m] = rowm[m]; mp.cnt_off[m] = m * 100000;
      mp.start[m] = s; s += Em[m];
    }
    mp.row[5] = batch; mp.cnt_off[5] = 500000; mp.start[5] = s;
    mp.total = s + NA;
  }
  (void)hipMemsetAsync(cnt, 0, (size_t)CNT_N * 4, stream);
  (void)hipMemsetAsync(acc, 0, (size_t)ACC_ROWS * 64 * 2, stream);
  k_count<<<2048, 256, 0, stream>>>(mp, cnt);
  int nbScan = (CNT_N + 2047) / 2048;  // 247
  k_scanA<<<nbScan, 256, 0, stream>>>(cnt, basea, bsums, CNT_N);
  k_scanB<<<1, 256, 0, stream>>>(bsums, nbScan);
  k_scanC<<<nbScan, 256, 0, stream>>>(basea, bsums, CNT_N);
  (void)hipMemcpyAsync(cursor, basea, (size_t)CNT_N * 4, hipMemcpyDeviceToDevice, stream);
  k_fill<<<2048, 256, 0, stream>>>(mp, cursor, bucket);

  // ---- prepack weights + feature init
  k_prepB<<<480, 256, 0, stream>>>(pK, cK, Bp);
  k_prepW<<<320, 256, 0, stream>>>(pW_p2a, cW_p2a, pW_a2p, cW_a2p, Wpk);
  k_atom_init<<<NA * 16 / 256, 256, 0, stream>>>(x_atom, aemb0, aemb1, aemb2, x);
  {
    PInit pp;
    int s8 = 0;
    for (int m = 0; m < 5; m++) {
      pp.dst[m] = xp[m];
      pp.vals[m] = vals[m];
      pp.tab[m] = (m < 3) ? (path_emb + m * 6 * 64) : (cycle_emb + (m - 3) * 4 * 64);
      pp.start8[m] = s8;
      s8 += Em[m] * 8;
    }
    pp.total8 = s8;
    k_path_init<<<8192, 256, 0, stream>>>(pp);
  }

  int apply_blocks = ACC_ROWS / 64;  // 1563

  // ---- layers: per group, batched fused (reads live x) -> per map scatter+apply
  for (int l = 0; l < 2; l++) {
    // === paths group (maps 0..2), non-cyclic
    {
      FusedParams fp{};
      fp.nseg = 3; fp.cyclic = 0; fp.xh = x;
      int bs = 0;
      for (int m = 0; m < 3; m++) {
        fp.gidx[m] = rowm[m]; fp.xp[m] = xp[m];
        fp.Wa[m] = Wpk + (size_t)(10 + l * 3 + m) * 4096;
        fp.ba[m] = pb_a2p + (l * 3 + m) * 64;
        fp.Bp[m] = Bp + (size_t)(l * 3 + m) * 12288;
        fp.Kb[m] = pKb + (l * 3 + m) * 64;
        fp.k[m] = Km[m]; fp.P[m] = Em[m] / Km[m]; fp.ppb[m] = Ppb[m];
        fp.blk_start[m] = bs;
        bs += (fp.P[m] + fp.ppb[m] - 1) / fp.ppb[m];
      }
      k_fused<<<bs, 256, 0, stream>>>(fp);

      for (int m = 0; m < 3; m++) {
        k_scatter<<<1024, 256, 0, stream>>>((const f16*)xp[m], bucket + MapStart[m],
                                            (__half2*)acc, Em[m]);
        k_apply<<<apply_blocks, 256, 0, stream>>>(acc, cnt + m * 100000,
                                                  Wpk + (size_t)(l * 3 + m) * 4096,
                                                  pb_p2a + (l * 3 + m) * 64, x);
      }
    }
    // === cycles group (maps 3..4), cyclic
    {
      FusedParams fp{};
      fp.nseg = 2; fp.cyclic = 1; fp.xh = x;
      int bs = 0;
      for (int m = 3; m < 5; m++) {
        int i = m - 3;
        fp.gidx[i] = rowm[m]; fp.xp[i] = xp[m];
        fp.Wa[i] = Wpk + (size_t)(16 + l * 2 + i) * 4096;
        fp.ba[i] = cb_a2p + (l * 2 + i) * 64;
        fp.Bp[i] = Bp + (size_t)(6 + l * 2 + i) * 12288;
        fp.Kb[i] = cKb + (l * 2 + i) * 64;
        fp.k[i] = Km[m]; fp.P[i] = Em[m] / Km[m]; fp.ppb[i] = Ppb[m];
        fp.blk_start[i] = bs;
        bs += (fp.P[i] + fp.ppb[i] - 1) / fp.ppb[i];
      }
      k_fused<<<bs, 256, 0, stream>>>(fp);

      for (int m = 3; m < 5; m++) {
        int i = m - 3;
        k_scatter<<<1024, 256, 0, stream>>>((const f16*)xp[m], bucket + MapStart[m],
                                            (__half2*)acc, Em[m]);
        k_apply<<<apply_blocks, 256, 0, stream>>>(acc, cnt + m * 100000,
                                                  Wpk + (size_t)(6 + l * 2 + i) * 4096,
                                                  cb_p2a + (l * 2 + i) * 64, x);
      }
    }
  }

  // ---- head
  k_meanscatter<<<NBATCH / 4, 256, 0, stream>>>(x, bucket, basea + 500000, cnt + 500000,
                                                g1, NBATCH);
  k_head<<<NBATCH / 32, 256, 0, stream>>>(g1, alW, alb, g2);
  k_final<<<NBATCH / 4, 256, 0, stream>>>(g2, linW, linb, (float*)d_out);
}

// Round 18
// 1100.049 us; speedup vs baseline: 1.9095x; 1.0095x over previous
//
#include <hip/hip_runtime.h>
#include <hip/hip_fp16.h>

#define NA 100000
#define NBATCH 4096
#define MLD 68
#define CLD2 66

typedef _Float16 f16;
typedef f16 half8 __attribute__((ext_vector_type(8)));
typedef f16 half4 __attribute__((ext_vector_type(4)));
typedef f16 hv2 __attribute__((ext_vector_type(2)));
typedef float f32x4 __attribute__((ext_vector_type(4)));
union H8 { uint4 u; __half h[8]; };
union HU { uint4 u; half8 h; f16 s[8]; };

// packed f16 atomic add (HW pk_add_f16 path)
__device__ inline void pk_atomic_add(__half2* addr, hv2 v) {
#if __has_builtin(__builtin_amdgcn_flat_atomic_fadd_v2f16)
  __builtin_amdgcn_flat_atomic_fadd_v2f16((hv2*)addr, v);
#else
  unsafeAtomicAdd(addr, *(__half2*)&v);
#endif
}

// ---------------- CSR build (5 maps + batch) ----------------

struct MapsParams {
  const int* row[6];
  int cnt_off[6];
  int start[6];
  int total;
};

__global__ __launch_bounds__(256) void k_count(MapsParams mp, int* cnt) {
  for (int g = blockIdx.x * 256 + threadIdx.x; g < mp.total; g += gridDim.x * 256) {
    int m = 0;
#pragma unroll
    for (int i = 1; i < 6; i++) if (g >= mp.start[i]) m = i;
    int e = g - mp.start[m];
    atomicAdd(&cnt[mp.cnt_off[m] + mp.row[m][e]], 1);
  }
}

__global__ __launch_bounds__(256) void k_scanA(const int* in, int* out, int* bsums, int n) {
  __shared__ int s[256];
  int t = threadIdx.x;
  int base = blockIdx.x * 2048 + t * 8;
  int v[8]; int sum = 0;
#pragma unroll
  for (int i = 0; i < 8; i++) { v[i] = (base + i < n) ? in[base + i] : 0; sum += v[i]; }
  s[t] = sum;
  __syncthreads();
  for (int d = 1; d < 256; d <<= 1) {
    int x = (t >= d) ? s[t - d] : 0;
    __syncthreads();
    s[t] += x;
    __syncthreads();
  }
  if (t == 255) bsums[blockIdx.x] = s[255];
  int run = s[t] - sum;
#pragma unroll
  for (int i = 0; i < 8; i++) { if (base + i < n) out[base + i] = run; run += v[i]; }
}

__global__ __launch_bounds__(256) void k_scanB(int* a, int n) {
  __shared__ int s[256];
  int t = threadIdx.x;
  int carry = 0;
  for (int c0 = 0; c0 < n; c0 += 256) {
    int v = (c0 + t < n) ? a[c0 + t] : 0;
    s[t] = v;
    __syncthreads();
    for (int d = 1; d < 256; d <<= 1) {
      int x = (t >= d) ? s[t - d] : 0;
      __syncthreads();
      s[t] += x;
      __syncthreads();
    }
    if (c0 + t < n) a[c0 + t] = s[t] - v + carry;
    int tot = s[255];
    __syncthreads();
    carry += tot;
  }
}

__global__ __launch_bounds__(256) void k_scanC(int* out, const int* bsums, int n) {
  int addv = bsums[blockIdx.x];
  int base = blockIdx.x * 2048 + threadIdx.x * 8;
#pragma unroll
  for (int i = 0; i < 8; i++) if (base + i < n) out[base + i] += addv;
}

// bucket stores EDGE id only (4B): halves scattered-write line traffic vs int2
__global__ __launch_bounds__(256) void k_fill(MapsParams mp, int* cursor, int* bucket) {
  for (int g = blockIdx.x * 256 + threadIdx.x; g < mp.total; g += gridDim.x * 256) {
    int m = 0;
#pragma unroll
    for (int i = 1; i < 6; i++) if (g >= mp.start[i]) m = i;
    int e = g - mp.start[m];
    int a = mp.row[m][e];
    int pos = atomicAdd(&cursor[mp.cnt_off[m] + a], 1);
    bucket[pos] = e;
  }
}

// ---------------- feature init (x stored f16) ----------------

__global__ __launch_bounds__(256) void k_atom_init(const int* xa, const float* e0,
                                                   const float* e1, const float* e2, f16* x) {
  int idx = blockIdx.x * 256 + threadIdx.x;
  if (idx >= NA * 16) return;
  int a = idx >> 4, q = idx & 15;
  int f0 = xa[a * 3], f1 = xa[a * 3 + 1], f2 = xa[a * 3 + 2];
  float4 v0 = ((const float4*)e0)[f0 * 16 + q];
  float4 v1 = ((const float4*)e1)[f1 * 16 + q];
  float4 v2 = ((const float4*)e2)[f2 * 16 + q];
  half4 h = {(f16)(v0.x + v1.x + v2.x), (f16)(v0.y + v1.y + v2.y),
             (f16)(v0.z + v1.z + v2.z), (f16)(v0.w + v1.w + v2.w)};
  ((half4*)x)[idx] = h;
}

struct PInit {
  __half* dst[5];
  const int* vals[5];
  const float* tab[5];
  int start8[5];
  int total8;
};

__global__ __launch_bounds__(256) void k_path_init(PInit pp) {
  for (int g = blockIdx.x * 256 + threadIdx.x; g < pp.total8; g += gridDim.x * 256) {
    int m = 0;
#pragma unroll
    for (int i = 1; i < 5; i++) if (g >= pp.start8[i]) m = i;
    int lc = g - pp.start8[m];
    int e = lc >> 3, q = lc & 7;
    int v = pp.vals[m][e];
    const float* src = pp.tab[m] + v * 64 + q * 8;
    H8 o;
#pragma unroll
    for (int j = 0; j < 8; j++) o.h[j] = __float2half(src[j]);
    ((uint4*)pp.dst[m])[lc] = o.u;
  }
}

// ---------------- prepack conv kernels to fp16 MFMA-B layout ----------------

__global__ __launch_bounds__(256) void k_prepB(const float* pK, const float* cK, f16* Bp) {
  int tid = blockIdx.x * 256 + threadIdx.x;
  if (tid >= 10 * 12288) return;
  int set = tid / 12288, pos = tid % 12288;
  int j = pos & 7, lane = (pos >> 3) & 63, kcnt = pos >> 9;
  int kc = kcnt % 6, nt = kcnt / 6;
  int k = kc * 32 + ((lane >> 4) << 3) + j;
  int n = (nt << 4) + (lane & 15);
  int w = k >> 6, ji = k & 63;
  const float* K = (set < 6) ? (pK + set * 3 * 4096) : (cK + (set - 6) * 3 * 4096);
  float v = K[w * 4096 + ji * 64 + n];
  if (set >= 6) v = 0.5f * (v + K[(2 - w) * 4096 + ji * 64 + n]);
  Bp[tid] = (f16)v;
}

// ---------------- prepack 64x64 weights to fp16 MFMA-B layout ----------------

__global__ __launch_bounds__(256) void k_prepW(const float* pW, const float* cW,
                                               const float* pWa, const float* cWa, f16* Wp) {
  int tid = blockIdx.x * 256 + threadIdx.x;
  if (tid >= 20 * 4096) return;
  int set = tid >> 12, pos = tid & 4095;
  int j = pos & 7, lane = (pos >> 3) & 63, ntkc = pos >> 9;
  int kc = ntkc & 1, nt = ntkc >> 1;
  int k = kc * 32 + ((lane >> 4) << 3) + j;
  int n = (nt << 4) + (lane & 15);
  const float* W;
  if (set < 6) W = pW + set * 4096;
  else if (set < 10) W = cW + (set - 6) * 4096;
  else if (set < 16) W = pWa + (set - 10) * 4096;
  else W = cWa + (set - 16) * 4096;
  Wp[tid] = (f16)W[k * 64 + n];
}

// ---------------- fused a2p+conv per map-group (batched segs) ----------------

struct FusedParams {
  const f16* xh;
  const int* gidx[3];
  __half* xp[3];
  const f16* Wa[3];
  const float* ba[3];
  const f16* Bp[3];
  const float* Kb[3];
  int k[3];
  int P[3];
  int ppb[3];
  int blk_start[3];
  int nseg;
  int cyclic;
};

__global__ __launch_bounds__(256) void k_fused(FusedParams p) {
  __shared__ uint4 CfU[1584];
  __shared__ uint4 xn4[873];
  __shared__ float bl[64], kbl[64];
  __shared__ int ridx[96];
  float* Cf = (float*)CfU;
  uint4* Af = CfU;
  int bid = blockIdx.x;
  int seg = 0;
#pragma unroll
  for (int i = 1; i < 3; i++) if (i < p.nseg && bid >= p.blk_start[i]) seg = i;
  int kk = p.k[seg], ppb = p.ppb[seg], P = p.P[seg];
  int cyc = p.cyclic;
  int t = threadIdx.x;
  int p0 = (bid - p.blk_start[seg]) * ppb;
  int np = min(ppb, P - p0);
  int R = np * kk;
  int mtb = R >> 4;
  long ebase = (long)p0 * kk;
  if (t < 64) { bl[t] = p.ba[seg][t]; kbl[t] = p.Kb[seg][t]; }
  if (t < 9) { uint4 z; z.x = z.y = z.z = z.w = 0; xn4[96 * 9 + t] = z; }
  if (t < R) ridx[t] = p.gidx[seg][ebase + t];
  __syncthreads();
  const uint4* xh4 = (const uint4*)p.xh;
  int nunits = mtb * 128;
  for (int j = t; j < nunits; j += 256) {
    int frag = j >> 6, lb = j & 63;
    int row = ((frag >> 1) << 4) + (lb & 15);
    int ch = ((frag & 1) << 2) + (lb >> 4);
    Af[j] = xh4[(long)ridx[row] * 8 + ch];
  }
  __syncthreads();
  int lane = t & 63, wid = t >> 6;
  int wave_n = wid & 1, wave_m = wid >> 1;
  int mtA = (mtb + 1) >> 1;
  int m0 = wave_m ? mtA : 0;
  int mcnt = wave_m ? (mtb - mtA) : mtA;
  f32x4 acc1[3][2];
#pragma unroll
  for (int i = 0; i < 3; i++)
#pragma unroll
    for (int jn = 0; jn < 2; jn++) { f32x4 z = {0.f, 0.f, 0.f, 0.f}; acc1[i][jn] = z; }
  const uint4* Wau = (const uint4*)p.Wa[seg];
#pragma unroll
  for (int kc = 0; kc < 2; kc++) {
    HU a[3], b[2];
#pragma unroll
    for (int jn = 0; jn < 2; jn++)
      b[jn].u = Wau[(((wave_n * 2 + jn) << 1) + kc) * 64 + lane];
#pragma unroll
    for (int i = 0; i < 3; i++)
      if (i < mcnt) a[i].u = Af[(((m0 + i) << 1) + kc) * 64 + lane];
#pragma unroll
    for (int i = 0; i < 3; i++)
      if (i < mcnt) {
#pragma unroll
        for (int jn = 0; jn < 2; jn++)
          acc1[i][jn] = __builtin_amdgcn_mfma_f32_16x16x32_f16(a[i].h, b[jn].h, acc1[i][jn], 0, 0, 0);
      }
  }
  __syncthreads();
#pragma unroll
  for (int i = 0; i < 3; i++) {
    if (i >= mcnt) continue;
#pragma unroll
    for (int jn = 0; jn < 2; jn++) {
      int n = ((wave_n * 2 + jn) << 4) + (lane & 15);
      float bv = bl[n];
      int rb = ((m0 + i) << 4) + ((lane >> 4) << 2);
#pragma unroll
      for (int reg = 0; reg < 4; reg++) {
        float v = acc1[i][jn][reg] + bv;
        Cf[(rb + reg) * CLD2 + n] = v > 0.f ? v : 0.f;
      }
    }
  }
  __syncthreads();
  uint4* xg = (uint4*)(p.xp[seg] + (long)ebase * 64);
  for (int idx = t; idx < R * 8; idx += 256) {
    int row = idx >> 3, ch = idx & 7;
    HU res; res.u = xg[idx];
    const float* c = &Cf[row * CLD2 + ch * 8];
    HU o;
#pragma unroll
    for (int j = 0; j < 8; j++) o.s[j] = (f16)((float)res.s[j] + c[j]);
    xn4[row * 9 + ch] = o.u;
  }
  __syncthreads();
  f32x4 acc2[3][2];
#pragma unroll
  for (int i = 0; i < 3; i++)
#pragma unroll
    for (int jn = 0; jn < 2; jn++) { f32x4 z = {0.f, 0.f, 0.f, 0.f}; acc2[i][jn] = z; }
  int rdw[3][3];
#pragma unroll
  for (int i = 0; i < 3; i++) {
    if (i >= mcnt) continue;
    int mr = ((m0 + i) << 4) + (lane & 15);
    int sm = mr % kk;
    rdw[i][1] = mr;
    rdw[i][0] = (sm >= 1) ? mr - 1 : (cyc ? mr + kk - 1 : 96);
    rdw[i][2] = (sm + 1 < kk) ? mr + 1 : (cyc ? mr + 1 - kk : 96);
  }
  const uint4* Bg = (const uint4*)p.Bp[seg];
  for (int kc = 0; kc < 6; kc++) {
    int w = kc >> 1;
    int chunk = ((kc & 1) << 2) + (lane >> 4);
    HU a[3], b[2];
#pragma unroll
    for (int jn = 0; jn < 2; jn++)
      b[jn].u = Bg[((wave_n * 2 + jn) * 6 + kc) * 64 + lane];
#pragma unroll
    for (int i = 0; i < 3; i++)
      if (i < mcnt) a[i].u = xn4[rdw[i][w] * 9 + chunk];
#pragma unroll
    for (int i = 0; i < 3; i++)
      if (i < mcnt) {
#pragma unroll
        for (int jn = 0; jn < 2; jn++)
          acc2[i][jn] = __builtin_amdgcn_mfma_f32_16x16x32_f16(a[i].h, b[jn].h, acc2[i][jn], 0, 0, 0);
      }
  }
  __syncthreads();
#pragma unroll
  for (int i = 0; i < 3; i++) {
    if (i >= mcnt) continue;
#pragma unroll
    for (int jn = 0; jn < 2; jn++) {
      int n = ((wave_n * 2 + jn) << 4) + (lane & 15);
      float bv = kbl[n];
      int rb = ((m0 + i) << 4) + ((lane >> 4) << 2);
#pragma unroll
      for (int reg = 0; reg < 4; reg++) {
        float v = acc2[i][jn][reg] + bv;
        Cf[(rb + reg) * CLD2 + n] = v > 0.f ? v : 0.f;
      }
    }
  }
  __syncthreads();
  for (int idx = t; idx < R * 8; idx += 256) {
    int row = idx >> 3, ch = idx & 7;
    HU res; res.u = xn4[row * 9 + ch];
    const float* c = &Cf[row * CLD2 + ch * 8];
    HU o;
#pragma unroll
    for (int j = 0; j < 8; j++) o.s[j] = (f16)((float)res.s[j] + c[j]);
    xg[idx] = o.u;
  }
}

// ---------------- p2a scatter v4: CSR-ordered aggregation; atom via row[e] -------------

__global__ __launch_bounds__(256) void k_scatter(const f16* xp, const int* bucket,
                                                 const int* row, __half2* acc, int E) {
  int ghw = (blockIdx.x * 256 + threadIdx.x) >> 5;
  int l = threadIdx.x & 31;
  int nhw = (gridDim.x * 256) >> 5;
  const hv2* xp2 = (const hv2*)xp;
  for (int j0 = ghw * 8; j0 < E; j0 += nhw * 8) {
    if (j0 + 8 <= E) {
      int e[8];
#pragma unroll
      for (int u = 0; u < 8; u++) e[u] = bucket[j0 + u];
      int a[8];
#pragma unroll
      for (int u = 0; u < 8; u++) a[u] = row[e[u]];
      hv2 v[8];
#pragma unroll
      for (int u = 0; u < 8; u++) v[u] = xp2[(long)e[u] * 32 + l];
      hv2 vacc = v[0];
      int cur = a[0];
#pragma unroll
      for (int u = 1; u < 8; u++) {
        if (a[u] == cur) {
          vacc = vacc + v[u];
        } else {
          pk_atomic_add(&acc[(long)cur * 32 + l], vacc);
          cur = a[u];
          vacc = v[u];
        }
      }
      pk_atomic_add(&acc[(long)cur * 32 + l], vacc);
    } else {
      int nc = E - j0;
      int e0 = bucket[j0];
      hv2 vacc = xp2[(long)e0 * 32 + l];
      int cur = row[e0];
      for (int u = 1; u < nc; u++) {
        int eu = bucket[j0 + u];
        hv2 v = xp2[(long)eu * 32 + l];
        int au = row[eu];
        if (au == cur) {
          vacc = vacc + v;
        } else {
          pk_atomic_add(&acc[(long)cur * 32 + l], vacc);
          cur = au;
          vacc = v;
        }
      }
      pk_atomic_add(&acc[(long)cur * 32 + l], vacc);
    }
  }
}

// ---------------- p2a apply: x += relu(acc/cnt @ W + b); x f16; self-zeroes acc ---------

__global__ __launch_bounds__(256) void k_apply(f16* acc, const int* cnt, const f16* Wp,
                                               const float* bias, f16* x) {
  __shared__ float mean[64 * MLD];
  __shared__ uint4 Af[512];
  __shared__ float invl[64];
  __shared__ float bl[64];
  int t = threadIdx.x;
  int a0 = blockIdx.x * 64;
  if (t < 64) {
    int cb = cnt[a0 + t];
    invl[t] = 1.f / (float)(cb > 0 ? cb : 1);
    bl[t] = bias[t];
  }
  uint4* acc4 = (uint4*)acc;
#pragma unroll
  for (int i = 0; i < 2; i++) {
    int idx = t + 256 * i;
    int r = idx >> 3, q = idx & 7;
    HU v; v.u = acc4[(long)a0 * 8 + idx];
    uint4 z4; z4.x = z4.y = z4.z = z4.w = 0;
    acc4[(long)a0 * 8 + idx] = z4;
    float* mr = &mean[r * MLD + q * 8];
#pragma unroll
    for (int j = 0; j < 8; j++) mr[j] = (float)v.s[j];
  }
  __syncthreads();
#pragma unroll
  for (int i = 0; i < 2; i++) {
    int j = t + 256 * i;
    int frag = j >> 6, lb = j & 63;
    int row = ((frag >> 1) << 4) + (lb & 15);
    int ch = ((frag & 1) << 2) + (lb >> 4);
    float inv = invl[row];
    const float* mr = &mean[row * MLD + ch * 8];
    HU o;
#pragma unroll
    for (int jj = 0; jj < 8; jj++) o.h[jj] = (f16)(mr[jj] * inv);
    Af[j] = o.u;
  }
  __syncthreads();
  int lane = t & 63, wid = t >> 6;
  HU af0, af1;
  af0.u = Af[((wid << 1) + 0) * 64 + lane];
  af1.u = Af[((wid << 1) + 1) * 64 + lane];
  const uint4* Wu = (const uint4*)Wp;
  int rowb = a0 + wid * 16 + ((lane >> 4) << 2);
#pragma unroll
  for (int nt = 0; nt < 4; nt++) {
    HU b0, b1;
    b0.u = Wu[((nt << 1) + 0) * 64 + lane];
    b1.u = Wu[((nt << 1) + 1) * 64 + lane];
    f32x4 z = {0.f, 0.f, 0.f, 0.f};
    z = __builtin_amdgcn_mfma_f32_16x16x32_f16(af0.h, b0.h, z, 0, 0, 0);
    z = __builtin_amdgcn_mfma_f32_16x16x32_f16(af1.h, b1.h, z, 0, 0, 0);
    int n = nt * 16 + (lane & 15);
    float bv = bl[n];
#pragma unroll
    for (int r = 0; r < 4; r++) {
      int atom = rowb + r;
      if (atom < NA) {
        float vv = z[r] + bv;
        vv = vv > 0.f ? vv : 0.f;
        long oi = (long)atom * 64 + n;
        x[oi] = (f16)((float)x[oi] + vv);
      }
    }
  }
}

// ---------------- batch mean over f16 x (bucket stores atom ids; basea is global) --------

__global__ __launch_bounds__(256) void k_meanscatter(const f16* src, const int* bucket,
                                                     const int* basea, const int* cnta,
                                                     float* dst, int nseg) {
  int wid = (blockIdx.x * 256 + threadIdx.x) >> 6;
  int lane = threadIdx.x & 63;
  if (wid >= nseg) return;
  int b0 = basea[wid], cnt = cnta[wid];
  float s = 0.f;
  for (int i = 0; i < cnt; i++) {
    int e = bucket[b0 + i];
    s += (float)src[(long)e * 64 + lane];
  }
  dst[(long)wid * 64 + lane] = s / (float)(cnt > 0 ? cnt : 1);
}

// ---------------- head gemm ----------------

__global__ __launch_bounds__(256) void k_head(const float* g1, const float* W,
                                              const float* bias, float* g2) {
  __shared__ float Wl[4096];
  __shared__ float inl[32 * 64];
  __shared__ float bl[64];
  int t = threadIdx.x;
  int brow = blockIdx.x * 32;
#pragma unroll
  for (int i = 0; i < 4; i++) ((float4*)Wl)[t + 256 * i] = ((const float4*)W)[t + 256 * i];
  if (t < 64) bl[t] = bias[t];
  __syncthreads();
#pragma unroll
  for (int i = 0; i < 2; i++) {
    int idx = t + 256 * i;
    int r = idx >> 4, q = idx & 15;
    ((float4*)inl)[idx] = ((const float4*)(g1 + (long)(brow + r) * 64))[q];
  }
  __syncthreads();
  int c = t & 63, rq = t >> 6;
  float acc[8];
#pragma unroll
  for (int i = 0; i < 8; i++) acc[i] = 0.f;
  for (int j = 0; j < 64; j += 4) {
    float w0 = Wl[(j + 0) * 64 + c], w1 = Wl[(j + 1) * 64 + c];
    float w2 = Wl[(j + 2) * 64 + c], w3 = Wl[(j + 3) * 64 + c];
#pragma unroll
    for (int i = 0; i < 8; i++) {
      int r = rq * 8 + i;
      float4 v = *(const float4*)&inl[r * 64 + j];
      acc[i] += v.x * w0 + v.y * w1 + v.z * w2 + v.w * w3;
    }
  }
#pragma unroll
  for (int i = 0; i < 8; i++) {
    long r = brow + rq * 8 + i;
    float v = acc[i] + bl[c];
    g2[r * 64 + c] = v > 0.f ? v : 0.f;
  }
}

__global__ __launch_bounds__(256) void k_final(const float* g2, const float* linW,
                                               const float* linb, float* out) {
  int wid = (blockIdx.x * 256 + threadIdx.x) >> 6;
  int lane = threadIdx.x & 63;
  if (wid >= NBATCH) return;
  float v = g2[(long)wid * 64 + lane] * linW[lane];
  for (int o = 32; o > 0; o >>= 1) v += __shfl_down(v, o, 64);
  if (lane == 0) out[wid] = v + linb[0];
}

__global__ __launch_bounds__(256) void k_zero_out(float* out, int n) {
  for (int i = blockIdx.x * 256 + threadIdx.x; i < n; i += gridDim.x * 256) out[i] = 0.f;
}

// ---------------- launcher ----------------

extern "C" void kernel_launch(void* const* d_in, const int* in_sizes, int n_in,
                              void* d_out, int out_size, void* d_ws, size_t ws_size,
                              hipStream_t stream) {
  (void)in_sizes; (void)n_in;

  const int* x_atom = (const int*)d_in[0];
  const int* vals[5] = {(const int*)d_in[1], (const int*)d_in[4], (const int*)d_in[7],
                        (const int*)d_in[10], (const int*)d_in[13]};
  const int* rowm[5] = {(const int*)d_in[2], (const int*)d_in[5], (const int*)d_in[8],
                        (const int*)d_in[11], (const int*)d_in[14]};
  const int* batch = (const int*)d_in[16];
  const float* aemb0 = (const float*)d_in[17];
  const float* aemb1 = (const float*)d_in[18];
  const float* aemb2 = (const float*)d_in[19];
  const float* path_emb = (const float*)d_in[20];
  const float* cycle_emb = (const float*)d_in[21];
  const float* pW_a2p = (const float*)d_in[22];
  const float* pb_a2p = (const float*)d_in[23];
  const float* pW_p2a = (const float*)d_in[24];
  const float* pb_p2a = (const float*)d_in[25];
  const float* pK = (const float*)d_in[26];
  const float* pKb = (const float*)d_in[27];
  const float* cW_a2p = (const float*)d_in[28];
  const float* cb_a2p = (const float*)d_in[29];
  const float* cW_p2a = (const float*)d_in[30];
  const float* cb_p2a = (const float*)d_in[31];
  const float* cK = (const float*)d_in[32];
  const float* cKb = (const float*)d_in[33];
  const float* alW = (const float*)d_in[34];
  const float* alb = (const float*)d_in[35];
  const float* linW = (const float*)d_in[36];
  const float* linb = (const float*)d_in[37];

  static const int Em[5] = {300000, 400000, 500000, 200000, 240000};
  static const int Km[5] = {3, 4, 5, 5, 6};
  static const int Ppb[5] = {32, 24, 16, 16, 16};
  static const int MapStart[5] = {0, 300000, 700000, 1200000, 1400000};
  const int CNT_N = 5 * 100000 + NBATCH;  // 504096
  const int BUCKET_N = 1640000 + NA;      // 1740000
  const int ACC_ROWS = 100032;

  char* ws = (char*)d_ws;
  size_t off = 0;
  auto alloc = [&](size_t nbytes) -> char* {
    char* p = ws + off;
    off = (off + nbytes + 255) & ~(size_t)255;
    return p;
  };
  f16* x = (f16*)alloc((size_t)NA * 64 * 2);   // f16 master
  __half* xp[5];
  for (int m = 0; m < 5; m++) xp[m] = (__half*)alloc((size_t)Em[m] * 64 * 2);
  f16* acc = (f16*)alloc((size_t)ACC_ROWS * 64 * 2);
  float* g1 = (float*)alloc((size_t)NBATCH * 64 * 4);
  float* g2 = (float*)alloc((size_t)NBATCH * 64 * 4);
  int* cnt = (int*)alloc((size_t)CNT_N * 4);
  int* basea = (int*)alloc((size_t)CNT_N * 4);
  int* cursor = (int*)alloc((size_t)CNT_N * 4);
  int* bucket = (int*)alloc((size_t)BUCKET_N * 4);
  int* bsums = (int*)alloc(256 * 4);
  f16* Bp = (f16*)alloc((size_t)10 * 12288 * 2);
  f16* Wpk = (f16*)alloc((size_t)20 * 4096 * 2);

  if (ws_size < off) {
    k_zero_out<<<16, 256, 0, stream>>>((float*)d_out, out_size);
    return;
  }

  // ---- CSR build (all maps + batch)
  MapsParams mp;
  {
    int s = 0;
    for (int m = 0; m < 5; m++) {
      mp.row[m] = rowm[m]; mp.cnt_off[m] = m * 100000;
      mp.start[m] = s; s += Em[m];
    }
    mp.row[5] = batch; mp.cnt_off[5] = 500000; mp.start[5] = s;
    mp.total = s + NA;
  }
  (void)hipMemsetAsync(cnt, 0, (size_t)CNT_N * 4, stream);
  (void)hipMemsetAsync(acc, 0, (size_t)ACC_ROWS * 64 * 2, stream);
  k_count<<<2048, 256, 0, stream>>>(mp, cnt);
  int nbScan = (CNT_N + 2047) / 2048;  // 247
  k_scanA<<<nbScan, 256, 0, stream>>>(cnt, basea, bsums, CNT_N);
  k_scanB<<<1, 256, 0, stream>>>(bsums, nbScan);
  k_scanC<<<nbScan, 256, 0, stream>>>(basea, bsums, CNT_N);
  (void)hipMemcpyAsync(cursor, basea, (size_t)CNT_N * 4, hipMemcpyDeviceToDevice, stream);
  k_fill<<<2048, 256, 0, stream>>>(mp, cursor, bucket);

  // ---- prepack weights + feature init
  k_prepB<<<480, 256, 0, stream>>>(pK, cK, Bp);
  k_prepW<<<320, 256, 0, stream>>>(pW_p2a, cW_p2a, pW_a2p, cW_a2p, Wpk);
  k_atom_init<<<NA * 16 / 256, 256, 0, stream>>>(x_atom, aemb0, aemb1, aemb2, x);
  {
    PInit pp;
    int s8 = 0;
    for (int m = 0; m < 5; m++) {
      pp.dst[m] = xp[m];
      pp.vals[m] = vals[m];
      pp.tab[m] = (m < 3) ? (path_emb + m * 6 * 64) : (cycle_emb + (m - 3) * 4 * 64);
      pp.start8[m] = s8;
      s8 += Em[m] * 8;
    }
    pp.total8 = s8;
    k_path_init<<<8192, 256, 0, stream>>>(pp);
  }

  int apply_blocks = ACC_ROWS / 64;  // 1563

  // ---- layers: per group, batched fused (reads live x) -> per map scatter+apply
  for (int l = 0; l < 2; l++) {
    // === paths group (maps 0..2), non-cyclic
    {
      FusedParams fp{};
      fp.nseg = 3; fp.cyclic = 0; fp.xh = x;
      int bs = 0;
      for (int m = 0; m < 3; m++) {
        fp.gidx[m] = rowm[m]; fp.xp[m] = xp[m];
        fp.Wa[m] = Wpk + (size_t)(10 + l * 3 + m) * 4096;
        fp.ba[m] = pb_a2p + (l * 3 + m) * 64;
        fp.Bp[m] = Bp + (size_t)(l * 3 + m) * 12288;
        fp.Kb[m] = pKb + (l * 3 + m) * 64;
        fp.k[m] = Km[m]; fp.P[m] = Em[m] / Km[m]; fp.ppb[m] = Ppb[m];
        fp.blk_start[m] = bs;
        bs += (fp.P[m] + fp.ppb[m] - 1) / fp.ppb[m];
      }
      k_fused<<<bs, 256, 0, stream>>>(fp);

      for (int m = 0; m < 3; m++) {
        k_scatter<<<1024, 256, 0, stream>>>((const f16*)xp[m], bucket + MapStart[m],
                                            rowm[m], (__half2*)acc, Em[m]);
        k_apply<<<apply_blocks, 256, 0, stream>>>(acc, cnt + m * 100000,
                                                  Wpk + (size_t)(l * 3 + m) * 4096,
                                                  pb_p2a + (l * 3 + m) * 64, x);
      }
    }
    // === cycles group (maps 3..4), cyclic
    {
      FusedParams fp{};
      fp.nseg = 2; fp.cyclic = 1; fp.xh = x;
      int bs = 0;
      for (int m = 3; m < 5; m++) {
        int i = m - 3;
        fp.gidx[i] = rowm[m]; fp.xp[i] = xp[m];
        fp.Wa[i] = Wpk + (size_t)(16 + l * 2 + i) * 4096;
        fp.ba[i] = cb_a2p + (l * 2 + i) * 64;
        fp.Bp[i] = Bp + (size_t)(6 + l * 2 + i) * 12288;
        fp.Kb[i] = cKb + (l * 2 + i) * 64;
        fp.k[i] = Km[m]; fp.P[i] = Em[m] / Km[m]; fp.ppb[i] = Ppb[m];
        fp.blk_start[i] = bs;
        bs += (fp.P[i] + fp.ppb[i] - 1) / fp.ppb[i];
      }
      k_fused<<<bs, 256, 0, stream>>>(fp);

      for (int m = 3; m < 5; m++) {
        int i = m - 3;
        k_scatter<<<1024, 256, 0, stream>>>((const f16*)xp[m], bucket + MapStart[m],
                                            rowm[m], (__half2*)acc, Em[m]);
        k_apply<<<apply_blocks, 256, 0, stream>>>(acc, cnt + m * 100000,
                                                  Wpk + (size_t)(6 + l * 2 + i) * 4096,
                                                  cb_p2a + (l * 2 + i) * 64, x);
      }
    }
  }

  // ---- head (basea entries for the batch segment are GLOBAL bucket positions)
  k_meanscatter<<<NBATCH / 4, 256, 0, stream>>>(x, bucket, basea + 500000,
                                                cnt + 500000, g1, NBATCH);
  k_head<<<NBATCH / 32, 256, 0, stream>>>(g1, alW, alb, g2);
  k_final<<<NBATCH / 4, 256, 0, stream>>>(g2, linW, linb, (float*)d_out);
}

// Round 19
// 1075.877 us; speedup vs baseline: 1.9524x; 1.0225x over previous
//
#include <hip/hip_runtime.h>
#include <hip/hip_fp16.h>

#define NA 100000
#define NBATCH 4096
#define MLD 68
#define CLD2 66

typedef _Float16 f16;
typedef f16 half8 __attribute__((ext_vector_type(8)));
typedef f16 half4 __attribute__((ext_vector_type(4)));
typedef f16 hv2 __attribute__((ext_vector_type(2)));
typedef float f32x4 __attribute__((ext_vector_type(4)));
union H8 { uint4 u; __half h[8]; };
union HU { uint4 u; half8 h; f16 s[8]; };

// packed f16 atomic add (HW pk_add_f16 path)
__device__ inline void pk_atomic_add(__half2* addr, hv2 v) {
#if __has_builtin(__builtin_amdgcn_flat_atomic_fadd_v2f16)
  __builtin_amdgcn_flat_atomic_fadd_v2f16((hv2*)addr, v);
#else
  unsafeAtomicAdd(addr, *(__half2*)&v);
#endif
}

// ---------------- CSR build (5 maps + batch) ----------------

struct MapsParams {
  const int* row[6];
  int cnt_off[6];
  int start[6];
  int total;
};

__global__ __launch_bounds__(256) void k_count(MapsParams mp, int* cnt) {
  for (int g = blockIdx.x * 256 + threadIdx.x; g < mp.total; g += gridDim.x * 256) {
    int m = 0;
#pragma unroll
    for (int i = 1; i < 6; i++) if (g >= mp.start[i]) m = i;
    int e = g - mp.start[m];
    atomicAdd(&cnt[mp.cnt_off[m] + mp.row[m][e]], 1);
  }
}

__global__ __launch_bounds__(256) void k_scanA(const int* in, int* out, int* bsums, int n) {
  __shared__ int s[256];
  int t = threadIdx.x;
  int base = blockIdx.x * 2048 + t * 8;
  int v[8]; int sum = 0;
#pragma unroll
  for (int i = 0; i < 8; i++) { v[i] = (base + i < n) ? in[base + i] : 0; sum += v[i]; }
  s[t] = sum;
  __syncthreads();
  for (int d = 1; d < 256; d <<= 1) {
    int x = (t >= d) ? s[t - d] : 0;
    __syncthreads();
    s[t] += x;
    __syncthreads();
  }
  if (t == 255) bsums[blockIdx.x] = s[255];
  int run = s[t] - sum;
#pragma unroll
  for (int i = 0; i < 8; i++) { if (base + i < n) out[base + i] = run; run += v[i]; }
}

__global__ __launch_bounds__(256) void k_scanB(int* a, int n) {
  __shared__ int s[256];
  int t = threadIdx.x;
  int carry = 0;
  for (int c0 = 0; c0 < n; c0 += 256) {
    int v = (c0 + t < n) ? a[c0 + t] : 0;
    s[t] = v;
    __syncthreads();
    for (int d = 1; d < 256; d <<= 1) {
      int x = (t >= d) ? s[t - d] : 0;
      __syncthreads();
      s[t] += x;
      __syncthreads();
    }
    if (c0 + t < n) a[c0 + t] = s[t] - v + carry;
    int tot = s[255];
    __syncthreads();
    carry += tot;
  }
}

__global__ __launch_bounds__(256) void k_scanC(int* out, const int* bsums, int n) {
  int addv = bsums[blockIdx.x];
  int base = blockIdx.x * 2048 + threadIdx.x * 8;
#pragma unroll
  for (int i = 0; i < 8; i++) if (base + i < n) out[base + i] += addv;
}

// bucket stores EDGE id only (4B)
__global__ __launch_bounds__(256) void k_fill(MapsParams mp, int* cursor, int* bucket) {
  for (int g = blockIdx.x * 256 + threadIdx.x; g < mp.total; g += gridDim.x * 256) {
    int m = 0;
#pragma unroll
    for (int i = 1; i < 6; i++) if (g >= mp.start[i]) m = i;
    int e = g - mp.start[m];
    int a = mp.row[m][e];
    int pos = atomicAdd(&cursor[mp.cnt_off[m] + a], 1);
    bucket[pos] = e;
  }
}

// ---------------- feature init (x stored f16) ----------------

__global__ __launch_bounds__(256) void k_atom_init(const int* xa, const float* e0,
                                                   const float* e1, const float* e2, f16* x) {
  int idx = blockIdx.x * 256 + threadIdx.x;
  if (idx >= NA * 16) return;
  int a = idx >> 4, q = idx & 15;
  int f0 = xa[a * 3], f1 = xa[a * 3 + 1], f2 = xa[a * 3 + 2];
  float4 v0 = ((const float4*)e0)[f0 * 16 + q];
  float4 v1 = ((const float4*)e1)[f1 * 16 + q];
  float4 v2 = ((const float4*)e2)[f2 * 16 + q];
  half4 h = {(f16)(v0.x + v1.x + v2.x), (f16)(v0.y + v1.y + v2.y),
             (f16)(v0.z + v1.z + v2.z), (f16)(v0.w + v1.w + v2.w)};
  ((half4*)x)[idx] = h;
}

struct PInit {
  __half* dst[5];
  const int* vals[5];
  const float* tab[5];
  int start8[5];
  int total8;
};

__global__ __launch_bounds__(256) void k_path_init(PInit pp) {
  for (int g = blockIdx.x * 256 + threadIdx.x; g < pp.total8; g += gridDim.x * 256) {
    int m = 0;
#pragma unroll
    for (int i = 1; i < 5; i++) if (g >= pp.start8[i]) m = i;
    int lc = g - pp.start8[m];
    int e = lc >> 3, q = lc & 7;
    int v = pp.vals[m][e];
    const float* src = pp.tab[m] + v * 64 + q * 8;
    H8 o;
#pragma unroll
    for (int j = 0; j < 8; j++) o.h[j] = __float2half(src[j]);
    ((uint4*)pp.dst[m])[lc] = o.u;
  }
}

// ---------------- prepack conv kernels to fp16 MFMA-B layout ----------------

__global__ __launch_bounds__(256) void k_prepB(const float* pK, const float* cK, f16* Bp) {
  int tid = blockIdx.x * 256 + threadIdx.x;
  if (tid >= 10 * 12288) return;
  int set = tid / 12288, pos = tid % 12288;
  int j = pos & 7, lane = (pos >> 3) & 63, kcnt = pos >> 9;
  int kc = kcnt % 6, nt = kcnt / 6;
  int k = kc * 32 + ((lane >> 4) << 3) + j;
  int n = (nt << 4) + (lane & 15);
  int w = k >> 6, ji = k & 63;
  const float* K = (set < 6) ? (pK + set * 3 * 4096) : (cK + (set - 6) * 3 * 4096);
  float v = K[w * 4096 + ji * 64 + n];
  if (set >= 6) v = 0.5f * (v + K[(2 - w) * 4096 + ji * 64 + n]);
  Bp[tid] = (f16)v;
}

// ---------------- prepack 64x64 weights to fp16 MFMA-B layout ----------------

__global__ __launch_bounds__(256) void k_prepW(const float* pW, const float* cW,
                                               const float* pWa, const float* cWa, f16* Wp) {
  int tid = blockIdx.x * 256 + threadIdx.x;
  if (tid >= 20 * 4096) return;
  int set = tid >> 12, pos = tid & 4095;
  int j = pos & 7, lane = (pos >> 3) & 63, ntkc = pos >> 9;
  int kc = ntkc & 1, nt = ntkc >> 1;
  int k = kc * 32 + ((lane >> 4) << 3) + j;
  int n = (nt << 4) + (lane & 15);
  const float* W;
  if (set < 6) W = pW + set * 4096;
  else if (set < 10) W = cW + (set - 6) * 4096;
  else if (set < 16) W = pWa + (set - 10) * 4096;
  else W = cWa + (set - 16) * 4096;
  Wp[tid] = (f16)W[k * 64 + n];
}

// ---------------- fused a2p+conv per map-group (batched segs) ----------------

struct FusedParams {
  const f16* xh;
  const int* gidx[3];
  __half* xp[3];
  const f16* Wa[3];
  const float* ba[3];
  const f16* Bp[3];
  const float* Kb[3];
  int k[3];
  int P[3];
  int ppb[3];
  int blk_start[3];
  int nseg;
  int cyclic;
};

__global__ __launch_bounds__(256) void k_fused(FusedParams p) {
  __shared__ uint4 CfU[1584];
  __shared__ uint4 xn4[873];
  __shared__ float bl[64], kbl[64];
  __shared__ int ridx[96];
  float* Cf = (float*)CfU;
  uint4* Af = CfU;
  int bid = blockIdx.x;
  int seg = 0;
#pragma unroll
  for (int i = 1; i < 3; i++) if (i < p.nseg && bid >= p.blk_start[i]) seg = i;
  int kk = p.k[seg], ppb = p.ppb[seg], P = p.P[seg];
  int cyc = p.cyclic;
  int t = threadIdx.x;
  int p0 = (bid - p.blk_start[seg]) * ppb;
  int np = min(ppb, P - p0);
  int R = np * kk;
  int mtb = R >> 4;
  long ebase = (long)p0 * kk;
  if (t < 64) { bl[t] = p.ba[seg][t]; kbl[t] = p.Kb[seg][t]; }
  if (t < 9) { uint4 z; z.x = z.y = z.z = z.w = 0; xn4[96 * 9 + t] = z; }
  if (t < R) ridx[t] = p.gidx[seg][ebase + t];
  __syncthreads();
  const uint4* xh4 = (const uint4*)p.xh;
  int nunits = mtb * 128;
  for (int j = t; j < nunits; j += 256) {
    int frag = j >> 6, lb = j & 63;
    int row = ((frag >> 1) << 4) + (lb & 15);
    int ch = ((frag & 1) << 2) + (lb >> 4);
    Af[j] = xh4[(long)ridx[row] * 8 + ch];
  }
  __syncthreads();
  int lane = t & 63, wid = t >> 6;
  int wave_n = wid & 1, wave_m = wid >> 1;
  int mtA = (mtb + 1) >> 1;
  int m0 = wave_m ? mtA : 0;
  int mcnt = wave_m ? (mtb - mtA) : mtA;
  f32x4 acc1[3][2];
#pragma unroll
  for (int i = 0; i < 3; i++)
#pragma unroll
    for (int jn = 0; jn < 2; jn++) { f32x4 z = {0.f, 0.f, 0.f, 0.f}; acc1[i][jn] = z; }
  const uint4* Wau = (const uint4*)p.Wa[seg];
#pragma unroll
  for (int kc = 0; kc < 2; kc++) {
    HU a[3], b[2];
#pragma unroll
    for (int jn = 0; jn < 2; jn++)
      b[jn].u = Wau[(((wave_n * 2 + jn) << 1) + kc) * 64 + lane];
#pragma unroll
    for (int i = 0; i < 3; i++)
      if (i < mcnt) a[i].u = Af[(((m0 + i) << 1) + kc) * 64 + lane];
#pragma unroll
    for (int i = 0; i < 3; i++)
      if (i < mcnt) {
#pragma unroll
        for (int jn = 0; jn < 2; jn++)
          acc1[i][jn] = __builtin_amdgcn_mfma_f32_16x16x32_f16(a[i].h, b[jn].h, acc1[i][jn], 0, 0, 0);
      }
  }
  __syncthreads();
#pragma unroll
  for (int i = 0; i < 3; i++) {
    if (i >= mcnt) continue;
#pragma unroll
    for (int jn = 0; jn < 2; jn++) {
      int n = ((wave_n * 2 + jn) << 4) + (lane & 15);
      float bv = bl[n];
      int rb = ((m0 + i) << 4) + ((lane >> 4) << 2);
#pragma unroll
      for (int reg = 0; reg < 4; reg++) {
        float v = acc1[i][jn][reg] + bv;
        Cf[(rb + reg) * CLD2 + n] = v > 0.f ? v : 0.f;
      }
    }
  }
  __syncthreads();
  uint4* xg = (uint4*)(p.xp[seg] + (long)ebase * 64);
  for (int idx = t; idx < R * 8; idx += 256) {
    int row = idx >> 3, ch = idx & 7;
    HU res; res.u = xg[idx];
    const float* c = &Cf[row * CLD2 + ch * 8];
    HU o;
#pragma unroll
    for (int j = 0; j < 8; j++) o.s[j] = (f16)((float)res.s[j] + c[j]);
    xn4[row * 9 + ch] = o.u;
  }
  __syncthreads();
  f32x4 acc2[3][2];
#pragma unroll
  for (int i = 0; i < 3; i++)
#pragma unroll
    for (int jn = 0; jn < 2; jn++) { f32x4 z = {0.f, 0.f, 0.f, 0.f}; acc2[i][jn] = z; }
  int rdw[3][3];
#pragma unroll
  for (int i = 0; i < 3; i++) {
    if (i >= mcnt) continue;
    int mr = ((m0 + i) << 4) + (lane & 15);
    int sm = mr % kk;
    rdw[i][1] = mr;
    rdw[i][0] = (sm >= 1) ? mr - 1 : (cyc ? mr + kk - 1 : 96);
    rdw[i][2] = (sm + 1 < kk) ? mr + 1 : (cyc ? mr + 1 - kk : 96);
  }
  const uint4* Bg = (const uint4*)p.Bp[seg];
  for (int kc = 0; kc < 6; kc++) {
    int w = kc >> 1;
    int chunk = ((kc & 1) << 2) + (lane >> 4);
    HU a[3], b[2];
#pragma unroll
    for (int jn = 0; jn < 2; jn++)
      b[jn].u = Bg[((wave_n * 2 + jn) * 6 + kc) * 64 + lane];
#pragma unroll
    for (int i = 0; i < 3; i++)
      if (i < mcnt) a[i].u = xn4[rdw[i][w] * 9 + chunk];
#pragma unroll
    for (int i = 0; i < 3; i++)
      if (i < mcnt) {
#pragma unroll
        for (int jn = 0; jn < 2; jn++)
          acc2[i][jn] = __builtin_amdgcn_mfma_f32_16x16x32_f16(a[i].h, b[jn].h, acc2[i][jn], 0, 0, 0);
      }
  }
  __syncthreads();
#pragma unroll
  for (int i = 0; i < 3; i++) {
    if (i >= mcnt) continue;
#pragma unroll
    for (int jn = 0; jn < 2; jn++) {
      int n = ((wave_n * 2 + jn) << 4) + (lane & 15);
      float bv = kbl[n];
      int rb = ((m0 + i) << 4) + ((lane >> 4) << 2);
#pragma unroll
      for (int reg = 0; reg < 4; reg++) {
        float v = acc2[i][jn][reg] + bv;
        Cf[(rb + reg) * CLD2 + n] = v > 0.f ? v : 0.f;
      }
    }
  }
  __syncthreads();
  for (int idx = t; idx < R * 8; idx += 256) {
    int row = idx >> 3, ch = idx & 7;
    HU res; res.u = xn4[row * 9 + ch];
    const float* c = &Cf[row * CLD2 + ch * 8];
    HU o;
#pragma unroll
    for (int j = 0; j < 8; j++) o.s[j] = (f16)((float)res.s[j] + c[j]);
    xg[idx] = o.u;
  }
}

// ---------------- p2a scatter v4: CSR-ordered aggregation; atom via row[e] -------------

__global__ __launch_bounds__(256) void k_scatter(const f16* xp, const int* bucket,
                                                 const int* row, __half2* acc, int E) {
  int ghw = (blockIdx.x * 256 + threadIdx.x) >> 5;
  int l = threadIdx.x & 31;
  int nhw = (gridDim.x * 256) >> 5;
  const hv2* xp2 = (const hv2*)xp;
  for (int j0 = ghw * 8; j0 < E; j0 += nhw * 8) {
    if (j0 + 8 <= E) {
      int e[8];
#pragma unroll
      for (int u = 0; u < 8; u++) e[u] = bucket[j0 + u];
      int a[8];
#pragma unroll
      for (int u = 0; u < 8; u++) a[u] = row[e[u]];
      hv2 v[8];
#pragma unroll
      for (int u = 0; u < 8; u++) v[u] = xp2[(long)e[u] * 32 + l];
      hv2 vacc = v[0];
      int cur = a[0];
#pragma unroll
      for (int u = 1; u < 8; u++) {
        if (a[u] == cur) {
          vacc = vacc + v[u];
        } else {
          pk_atomic_add(&acc[(long)cur * 32 + l], vacc);
          cur = a[u];
          vacc = v[u];
        }
      }
      pk_atomic_add(&acc[(long)cur * 32 + l], vacc);
    } else {
      int nc = E - j0;
      int e0 = bucket[j0];
      hv2 vacc = xp2[(long)e0 * 32 + l];
      int cur = row[e0];
      for (int u = 1; u < nc; u++) {
        int eu = bucket[j0 + u];
        hv2 v = xp2[(long)eu * 32 + l];
        int au = row[eu];
        if (au == cur) {
          vacc = vacc + v;
        } else {
          pk_atomic_add(&acc[(long)cur * 32 + l], vacc);
          cur = au;
          vacc = v;
        }
      }
      pk_atomic_add(&acc[(long)cur * 32 + l], vacc);
    }
  }
}

// ---------------- p2a apply (1 or 2 maps): x += sum_m relu(acc_m/cnt_m @ W_m + b_m) -----
// zeroes each acc tile after reading; single x read-modify-write.

struct ApplyParams {
  f16* acc[2];
  const int* cnt[2];
  const f16* Wp[2];
  const float* bias[2];
  int nm;
};

__global__ __launch_bounds__(256) void k_apply(ApplyParams p, f16* x) {
  __shared__ float mean[64 * MLD];
  __shared__ uint4 Af[512];
  __shared__ float invl[64];
  __shared__ float bl[64];
  int t = threadIdx.x;
  int a0 = blockIdx.x * 64;
  int lane = t & 63, wid = t >> 6;
  f32x4 addv[4];
#pragma unroll
  for (int nt = 0; nt < 4; nt++) { f32x4 z = {0.f, 0.f, 0.f, 0.f}; addv[nt] = z; }
  for (int mi = 0; mi < p.nm; mi++) {
    __syncthreads();  // prior iteration's Af reads / mean reads complete
    if (t < 64) {
      int cb = p.cnt[mi][a0 + t];
      invl[t] = 1.f / (float)(cb > 0 ? cb : 1);
      bl[t] = p.bias[mi][t];
    }
    uint4* acc4 = (uint4*)p.acc[mi];
#pragma unroll
    for (int i = 0; i < 2; i++) {
      int idx = t + 256 * i;
      int r = idx >> 3, q = idx & 7;
      HU v; v.u = acc4[(long)a0 * 8 + idx];
      uint4 z4; z4.x = z4.y = z4.z = z4.w = 0;
      acc4[(long)a0 * 8 + idx] = z4;
      float* mr = &mean[r * MLD + q * 8];
#pragma unroll
      for (int j = 0; j < 8; j++) mr[j] = (float)v.s[j];
    }
    __syncthreads();
#pragma unroll
    for (int i = 0; i < 2; i++) {
      int j = t + 256 * i;
      int frag = j >> 6, lb = j & 63;
      int row = ((frag >> 1) << 4) + (lb & 15);
      int ch = ((frag & 1) << 2) + (lb >> 4);
      float inv = invl[row];
      const float* mr = &mean[row * MLD + ch * 8];
      HU o;
#pragma unroll
      for (int jj = 0; jj < 8; jj++) o.h[jj] = (f16)(mr[jj] * inv);
      Af[j] = o.u;
    }
    __syncthreads();
    HU af0, af1;
    af0.u = Af[((wid << 1) + 0) * 64 + lane];
    af1.u = Af[((wid << 1) + 1) * 64 + lane];
    const uint4* Wu = (const uint4*)p.Wp[mi];
#pragma unroll
    for (int nt = 0; nt < 4; nt++) {
      HU b0, b1;
      b0.u = Wu[((nt << 1) + 0) * 64 + lane];
      b1.u = Wu[((nt << 1) + 1) * 64 + lane];
      f32x4 z = {0.f, 0.f, 0.f, 0.f};
      z = __builtin_amdgcn_mfma_f32_16x16x32_f16(af0.h, b0.h, z, 0, 0, 0);
      z = __builtin_amdgcn_mfma_f32_16x16x32_f16(af1.h, b1.h, z, 0, 0, 0);
      float bv = bl[nt * 16 + (lane & 15)];
#pragma unroll
      for (int r = 0; r < 4; r++) {
        float vv = z[r] + bv;
        addv[nt][r] += vv > 0.f ? vv : 0.f;
      }
    }
  }
  // single x read-modify-write
  int rowb = a0 + wid * 16 + ((lane >> 4) << 2);
#pragma unroll
  for (int nt = 0; nt < 4; nt++) {
    int n = nt * 16 + (lane & 15);
#pragma unroll
    for (int r = 0; r < 4; r++) {
      int atom = rowb + r;
      if (atom < NA) {
        long oi = (long)atom * 64 + n;
        x[oi] = (f16)((float)x[oi] + addv[nt][r]);
      }
    }
  }
}

// ---------------- batch mean over f16 x (bucket stores atom ids; basea is global) --------

__global__ __launch_bounds__(256) void k_meanscatter(const f16* src, const int* bucket,
                                                     const int* basea, const int* cnta,
                                                     float* dst, int nseg) {
  int wid = (blockIdx.x * 256 + threadIdx.x) >> 6;
  int lane = threadIdx.x & 63;
  if (wid >= nseg) return;
  int b0 = basea[wid], cnt = cnta[wid];
  float s = 0.f;
  for (int i = 0; i < cnt; i++) {
    int e = bucket[b0 + i];
    s += (float)src[(long)e * 64 + lane];
  }
  dst[(long)wid * 64 + lane] = s / (float)(cnt > 0 ? cnt : 1);
}

// ---------------- head gemm ----------------

__global__ __launch_bounds__(256) void k_head(const float* g1, const float* W,
                                              const float* bias, float* g2) {
  __shared__ float Wl[4096];
  __shared__ float inl[32 * 64];
  __shared__ float bl[64];
  int t = threadIdx.x;
  int brow = blockIdx.x * 32;
#pragma unroll
  for (int i = 0; i < 4; i++) ((float4*)Wl)[t + 256 * i] = ((const float4*)W)[t + 256 * i];
  if (t < 64) bl[t] = bias[t];
  __syncthreads();
#pragma unroll
  for (int i = 0; i < 2; i++) {
    int idx = t + 256 * i;
    int r = idx >> 4, q = idx & 15;
    ((float4*)inl)[idx] = ((const float4*)(g1 + (long)(brow + r) * 64))[q];
  }
  __syncthreads();
  int c = t & 63, rq = t >> 6;
  float acc[8];
#pragma unroll
  for (int i = 0; i < 8; i++) acc[i] = 0.f;
  for (int j = 0; j < 64; j += 4) {
    float w0 = Wl[(j + 0) * 64 + c], w1 = Wl[(j + 1) * 64 + c];
    float w2 = Wl[(j + 2) * 64 + c], w3 = Wl[(j + 3) * 64 + c];
#pragma unroll
    for (int i = 0; i < 8; i++) {
      int r = rq * 8 + i;
      float4 v = *(const float4*)&inl[r * 64 + j];
      acc[i] += v.x * w0 + v.y * w1 + v.z * w2 + v.w * w3;
    }
  }
#pragma unroll
  for (int i = 0; i < 8; i++) {
    long r = brow + rq * 8 + i;
    float v = acc[i] + bl[c];
    g2[r * 64 + c] = v > 0.f ? v : 0.f;
  }
}

__global__ __launch_bounds__(256) void k_final(const float* g2, const float* linW,
                                               const float* linb, float* out) {
  int wid = (blockIdx.x * 256 + threadIdx.x) >> 6;
  int lane = threadIdx.x & 63;
  if (wid >= NBATCH) return;
  float v = g2[(long)wid * 64 + lane] * linW[lane];
  for (int o = 32; o > 0; o >>= 1) v += __shfl_down(v, o, 64);
  if (lane == 0) out[wid] = v + linb[0];
}

__global__ __launch_bounds__(256) void k_zero_out(float* out, int n) {
  for (int i = blockIdx.x * 256 + threadIdx.x; i < n; i += gridDim.x * 256) out[i] = 0.f;
}

// ---------------- launcher ----------------

extern "C" void kernel_launch(void* const* d_in, const int* in_sizes, int n_in,
                              void* d_out, int out_size, void* d_ws, size_t ws_size,
                              hipStream_t stream) {
  (void)in_sizes; (void)n_in;

  const int* x_atom = (const int*)d_in[0];
  const int* vals[5] = {(const int*)d_in[1], (const int*)d_in[4], (const int*)d_in[7],
                        (const int*)d_in[10], (const int*)d_in[13]};
  const int* rowm[5] = {(const int*)d_in[2], (const int*)d_in[5], (const int*)d_in[8],
                        (const int*)d_in[11], (const int*)d_in[14]};
  const int* batch = (const int*)d_in[16];
  const float* aemb0 = (const float*)d_in[17];
  const float* aemb1 = (const float*)d_in[18];
  const float* aemb2 = (const float*)d_in[19];
  const float* path_emb = (const float*)d_in[20];
  const float* cycle_emb = (const float*)d_in[21];
  const float* pW_a2p = (const float*)d_in[22];
  const float* pb_a2p = (const float*)d_in[23];
  const float* pW_p2a = (const float*)d_in[24];
  const float* pb_p2a = (const float*)d_in[25];
  const float* pK = (const float*)d_in[26];
  const float* pKb = (const float*)d_in[27];
  const float* cW_a2p = (const float*)d_in[28];
  const float* cb_a2p = (const float*)d_in[29];
  const float* cW_p2a = (const float*)d_in[30];
  const float* cb_p2a = (const float*)d_in[31];
  const float* cK = (const float*)d_in[32];
  const float* cKb = (const float*)d_in[33];
  const float* alW = (const float*)d_in[34];
  const float* alb = (const float*)d_in[35];
  const float* linW = (const float*)d_in[36];
  const float* linb = (const float*)d_in[37];

  static const int Em[5] = {300000, 400000, 500000, 200000, 240000};
  static const int Km[5] = {3, 4, 5, 5, 6};
  static const int Ppb[5] = {32, 24, 16, 16, 16};
  static const int MapStart[5] = {0, 300000, 700000, 1200000, 1400000};
  const int CNT_N = 5 * 100000 + NBATCH;  // 504096
  const int BUCKET_N = 1640000 + NA;      // 1740000
  const int ACC_ROWS = 100032;

  char* ws = (char*)d_ws;
  size_t off = 0;
  auto alloc = [&](size_t nbytes) -> char* {
    char* p = ws + off;
    off = (off + nbytes + 255) & ~(size_t)255;
    return p;
  };
  f16* x = (f16*)alloc((size_t)NA * 64 * 2);   // f16 master
  __half* xp[5];
  for (int m = 0; m < 5; m++) xp[m] = (__half*)alloc((size_t)Em[m] * 64 * 2);
  f16* accA = (f16*)alloc((size_t)ACC_ROWS * 64 * 2);
  f16* accB = (f16*)alloc((size_t)ACC_ROWS * 64 * 2);
  float* g1 = (float*)alloc((size_t)NBATCH * 64 * 4);
  float* g2 = (float*)alloc((size_t)NBATCH * 64 * 4);
  int* cnt = (int*)alloc((size_t)CNT_N * 4);
  int* basea = (int*)alloc((size_t)CNT_N * 4);
  int* cursor = (int*)alloc((size_t)CNT_N * 4);
  int* bucket = (int*)alloc((size_t)BUCKET_N * 4);
  int* bsums = (int*)alloc(256 * 4);
  f16* Bp = (f16*)alloc((size_t)10 * 12288 * 2);
  f16* Wpk = (f16*)alloc((size_t)20 * 4096 * 2);

  if (ws_size < off) {
    k_zero_out<<<16, 256, 0, stream>>>((float*)d_out, out_size);
    return;
  }

  // ---- CSR build (all maps + batch)
  MapsParams mp;
  {
    int s = 0;
    for (int m = 0; m < 5; m++) {
      mp.row[m] = rowm[m]; mp.cnt_off[m] = m * 100000;
      mp.start[m] = s; s += Em[m];
    }
    mp.row[5] = batch; mp.cnt_off[5] = 500000; mp.start[5] = s;
    mp.total = s + NA;
  }
  (void)hipMemsetAsync(cnt, 0, (size_t)CNT_N * 4, stream);
  (void)hipMemsetAsync(accA, 0, (size_t)ACC_ROWS * 64 * 2, stream);
  (void)hipMemsetAsync(accB, 0, (size_t)ACC_ROWS * 64 * 2, stream);
  k_count<<<2048, 256, 0, stream>>>(mp, cnt);
  int nbScan = (CNT_N + 2047) / 2048;  // 247
  k_scanA<<<nbScan, 256, 0, stream>>>(cnt, basea, bsums, CNT_N);
  k_scanB<<<1, 256, 0, stream>>>(bsums, nbScan);
  k_scanC<<<nbScan, 256, 0, stream>>>(basea, bsums, CNT_N);
  (void)hipMemcpyAsync(cursor, basea, (size_t)CNT_N * 4, hipMemcpyDeviceToDevice, stream);
  k_fill<<<2048, 256, 0, stream>>>(mp, cursor, bucket);

  // ---- prepack weights + feature init
  k_prepB<<<480, 256, 0, stream>>>(pK, cK, Bp);
  k_prepW<<<320, 256, 0, stream>>>(pW_p2a, cW_p2a, pW_a2p, cW_a2p, Wpk);
  k_atom_init<<<NA * 16 / 256, 256, 0, stream>>>(x_atom, aemb0, aemb1, aemb2, x);
  {
    PInit pp;
    int s8 = 0;
    for (int m = 0; m < 5; m++) {
      pp.dst[m] = xp[m];
      pp.vals[m] = vals[m];
      pp.tab[m] = (m < 3) ? (path_emb + m * 6 * 64) : (cycle_emb + (m - 3) * 4 * 64);
      pp.start8[m] = s8;
      s8 += Em[m] * 8;
    }
    pp.total8 = s8;
    k_path_init<<<8192, 256, 0, stream>>>(pp);
  }

  int apply_blocks = ACC_ROWS / 64;  // 1563

  // weight/bias lookup helpers (p2a prepacked set + bias per map)
  auto p2aW = [&](int l, int m) -> const f16* {
    return (m < 3) ? Wpk + (size_t)(l * 3 + m) * 4096
                   : Wpk + (size_t)(6 + l * 2 + (m - 3)) * 4096;
  };
  auto p2aB = [&](int l, int m) -> const float* {
    return (m < 3) ? pb_p2a + (l * 3 + m) * 64 : cb_p2a + (l * 2 + (m - 3)) * 64;
  };

  // ---- layers: per group, batched fused -> scatters into 2 accs -> paired applies
  for (int l = 0; l < 2; l++) {
    // === paths group (maps 0..2), non-cyclic
    {
      FusedParams fp{};
      fp.nseg = 3; fp.cyclic = 0; fp.xh = x;
      int bs = 0;
      for (int m = 0; m < 3; m++) {
        fp.gidx[m] = rowm[m]; fp.xp[m] = xp[m];
        fp.Wa[m] = Wpk + (size_t)(10 + l * 3 + m) * 4096;
        fp.ba[m] = pb_a2p + (l * 3 + m) * 64;
        fp.Bp[m] = Bp + (size_t)(l * 3 + m) * 12288;
        fp.Kb[m] = pKb + (l * 3 + m) * 64;
        fp.k[m] = Km[m]; fp.P[m] = Em[m] / Km[m]; fp.ppb[m] = Ppb[m];
        fp.blk_start[m] = bs;
        bs += (fp.P[m] + fp.ppb[m] - 1) / fp.ppb[m];
      }
      k_fused<<<bs, 256, 0, stream>>>(fp);

      // maps 0,1 -> accA,accB; one paired apply
      k_scatter<<<1024, 256, 0, stream>>>((const f16*)xp[0], bucket + MapStart[0],
                                          rowm[0], (__half2*)accA, Em[0]);
      k_scatter<<<1024, 256, 0, stream>>>((const f16*)xp[1], bucket + MapStart[1],
                                          rowm[1], (__half2*)accB, Em[1]);
      {
        ApplyParams ap{};
        ap.nm = 2;
        ap.acc[0] = accA; ap.cnt[0] = cnt + 0 * 100000; ap.Wp[0] = p2aW(l, 0); ap.bias[0] = p2aB(l, 0);
        ap.acc[1] = accB; ap.cnt[1] = cnt + 1 * 100000; ap.Wp[1] = p2aW(l, 1); ap.bias[1] = p2aB(l, 1);
        k_apply<<<apply_blocks, 256, 0, stream>>>(ap, x);
      }
      // map 2 -> accA; single apply
      k_scatter<<<1024, 256, 0, stream>>>((const f16*)xp[2], bucket + MapStart[2],
                                          rowm[2], (__half2*)accA, Em[2]);
      {
        ApplyParams ap{};
        ap.nm = 1;
        ap.acc[0] = accA; ap.cnt[0] = cnt + 2 * 100000; ap.Wp[0] = p2aW(l, 2); ap.bias[0] = p2aB(l, 2);
        k_apply<<<apply_blocks, 256, 0, stream>>>(ap, x);
      }
    }
    // === cycles group (maps 3..4), cyclic
    {
      FusedParams fp{};
      fp.nseg = 2; fp.cyclic = 1; fp.xh = x;
      int bs = 0;
      for (int m = 3; m < 5; m++) {
        int i = m - 3;
        fp.gidx[i] = rowm[m]; fp.xp[i] = xp[m];
        fp.Wa[i] = Wpk + (size_t)(16 + l * 2 + i) * 4096;
        fp.ba[i] = cb_a2p + (l * 2 + i) * 64;
        fp.Bp[i] = Bp + (size_t)(6 + l * 2 + i) * 12288;
        fp.Kb[i] = cKb + (l * 2 + i) * 64;
        fp.k[i] = Km[m]; fp.P[i] = Em[m] / Km[m]; fp.ppb[i] = Ppb[m];
        fp.blk_start[i] = bs;
        bs += (fp.P[i] + fp.ppb[i] - 1) / fp.ppb[i];
      }
      k_fused<<<bs, 256, 0, stream>>>(fp);

      k_scatter<<<1024, 256, 0, stream>>>((const f16*)xp[3], bucket + MapStart[3],
                                          rowm[3], (__half2*)accA, Em[3]);
      k_scatter<<<1024, 256, 0, stream>>>((const f16*)xp[4], bucket + MapStart[4],
                                          rowm[4], (__half2*)accB, Em[4]);
      {
        ApplyParams ap{};
        ap.nm = 2;
        ap.acc[0] = accA; ap.cnt[0] = cnt + 3 * 100000; ap.Wp[0] = p2aW(l, 3); ap.bias[0] = p2aB(l, 3);
        ap.acc[1] = accB; ap.cnt[1] = cnt + 4 * 100000; ap.Wp[1] = p2aW(l, 4); ap.bias[1] = p2aB(l, 4);
        k_apply<<<apply_blocks, 256, 0, stream>>>(ap, x);
      }
    }
  }

  // ---- head (basea entries for the batch segment are GLOBAL bucket positions)
  k_meanscatter<<<NBATCH / 4, 256, 0, stream>>>(x, bucket, basea + 500000,
                                                cnt + 500000, g1, NBATCH);
  k_head<<<NBATCH / 32, 256, 0, stream>>>(g1, alW, alb, g2);
  k_final<<<NBATCH / 4, 256, 0, stream>>>(g2, linW, linb, (float*)d_out);
}